// Round 1
// baseline (1641.869 us; speedup 1.0000x reference)
//
#include <hip/hip_runtime.h>
#include <cstdint>

#define B_    4
#define S_    2048
#define D_    1024
#define NIN   8192
#define NPROC 4096
#define DR    256
#define DR2   512
#define KIN   4096
#define KPROC 2048

typedef _Float16 v8h  __attribute__((ext_vector_type(8)));
typedef _Float16 v4h  __attribute__((ext_vector_type(4)));
typedef float    v4f  __attribute__((ext_vector_type(4)));
typedef float    v16f __attribute__((ext_vector_type(16)));

__device__ __forceinline__ float geluf(float v) {
    return 0.5f * v * (1.0f + erff(v * 0.70710678f));
}

// async global->LDS, 16B per lane. LDS dest semantics: wave-uniform base + lane*16.
__device__ __forceinline__ void cp16(void* lds, const void* g) {
    __builtin_amdgcn_global_load_lds(
        (const __attribute__((address_space(1))) unsigned int*)g,
        (__attribute__((address_space(3))) unsigned int*)lds, 16, 0, 0);
}

// ---------------- converts ----------------
__global__ void k_conv_x16(const float* __restrict__ x, _Float16* __restrict__ x16, int n4) {
    int i = blockIdx.x * 256 + threadIdx.x;
    if (i < n4) {
        float4 v = ((const float4*)x)[i];
        v4h h = { (_Float16)v.x, (_Float16)v.y, (_Float16)v.z, (_Float16)v.w };
        ((v4h*)x16)[i] = h;
    }
}

__global__ void k_conv_split(const float* __restrict__ p, _Float16* __restrict__ ph,
                             _Float16* __restrict__ pl, int n) {
    int i = blockIdx.x * 256 + threadIdx.x;
    if (i < n) {
        float v = p[i];
        _Float16 h = (_Float16)v;
        ph[i] = h;
        pl[i] = (_Float16)(v - (float)h);
    }
}

// ---------------- gc = max over s ----------------
__global__ void k_max1(const float* __restrict__ x, float* __restrict__ pmax) {
    int d = blockIdx.x * 256 + threadIdx.x;
    int chunk = blockIdx.y;
    int b = blockIdx.z;
    const float* base = x + ((size_t)b * S_ + chunk * 128) * D_ + d;
    float m = -3.4e38f;
    for (int s = 0; s < 128; s++) m = fmaxf(m, base[(size_t)s * D_]);
    pmax[((size_t)b * 16 + chunk) * D_ + d] = m;
}

__global__ void k_max2(const float* __restrict__ pmax, double* __restrict__ gc64) {
    int d = blockIdx.x * 256 + threadIdx.x;
    int b = blockIdx.y;
    float m = -3.4e38f;
    for (int c = 0; c < 16; c++) m = fmaxf(m, pmax[((size_t)b * 16 + c) * D_ + d]);
    gc64[(size_t)b * D_ + d] = (double)m;
}

// ---------------- router (fp64) ----------------
__global__ __launch_bounds__(256) void k_router1(
    const double* __restrict__ gc64, const float* __restrict__ W1, const float* __restrict__ b1,
    double* __restrict__ hpre)
{
    int wave = threadIdx.x >> 6, lane = threadIdx.x & 63;
    int j = blockIdx.x * 4 + wave;
    int b = blockIdx.y;
    const double* g = gc64 + (size_t)b * D_;
    const float* w = W1 + (size_t)j * D_;
    double acc = 0.0;
    for (int d = lane; d < D_; d += 64) acc += g[d] * (double)w[d];
#pragma unroll
    for (int o = 32; o > 0; o >>= 1) acc += __shfl_xor(acc, o, 64);
    if (lane == 0) {
        double z = acc + (double)b1[j];
        hpre[(size_t)b * DR2 + j] = 0.5 * z * (1.0 + erf(z * 0.7071067811865475244));
    }
}

__global__ __launch_bounds__(512) void k_router2(
    const double* __restrict__ hpre, const float* __restrict__ lng, const float* __restrict__ lnb,
    const float* __restrict__ W2, const float* __restrict__ b2, double* __restrict__ qs)
{
    __shared__ double sh[DR2];
    __shared__ double red[DR2];
    int b = blockIdx.x, j = threadIdx.x;
    double ge = hpre[(size_t)b * DR2 + j];
    sh[j] = ge; red[j] = ge;
    __syncthreads();
    for (int s = 256; s > 0; s >>= 1) { if (j < s) red[j] += red[j + s]; __syncthreads(); }
    double mu = red[0] / 512.0;
    __syncthreads();
    double dv = ge - mu;
    red[j] = dv * dv;
    __syncthreads();
    for (int s = 256; s > 0; s >>= 1) { if (j < s) red[j] += red[j + s]; __syncthreads(); }
    double rs = 1.0 / sqrt(red[0] / 512.0 + 1e-5);
    __syncthreads();
    sh[j] = dv * rs * (double)lng[j] + (double)lnb[j];
    __syncthreads();
    if (j < DR) {
        double q = (double)b2[j];
        const float* w2r = W2 + (size_t)j * DR2;
        for (int t = 0; t < DR2; t++) q += sh[t] * (double)w2r[t];
        qs[(size_t)b * DR + j] = q;
    }
}

__global__ __launch_bounds__(256) void k_router3(
    const double* __restrict__ qs, const float* __restrict__ keys, double* __restrict__ logits)
{
    int wave = threadIdx.x >> 6, lane = threadIdx.x & 63;
    int n = blockIdx.x * 4 + wave;
    int b = blockIdx.y;
    const double* q = qs + (size_t)b * DR;
    const float* kr = keys + (size_t)n * DR;
    double acc = 0.0;
#pragma unroll
    for (int t = 0; t < 4; t++) {
        int d = lane + t * 64;
        acc += q[d] * (double)kr[d];
    }
#pragma unroll
    for (int o = 32; o > 0; o >>= 1) acc += __shfl_xor(acc, o, 64);
    if (lane == 0) logits[(size_t)b * NIN + n] = acc * 0.0625;
}

// ---------------- top-k ----------------
template<int N, int K>
__global__ __launch_bounds__(1024) void k_topk(const double* __restrict__ vals, int* __restrict__ outIdx) {
    __shared__ unsigned long long keys[N];
    int b = blockIdx.x, tid = threadIdx.x;
    for (int i = tid; i < N; i += 1024) {
        float v = (float)vals[(size_t)b * N + i];
        unsigned int u = __float_as_uint(v);
        u = (u & 0x80000000u) ? ~u : (u | 0x80000000u);
        keys[i] = ((unsigned long long)u << 32) | (unsigned int)(~i);
    }
    __syncthreads();
    for (int k = 2; k <= N; k <<= 1)
        for (int j = k >> 1; j > 0; j >>= 1) {
            for (int i = tid; i < N; i += 1024) {
                int l = i ^ j;
                if (l > i) {
                    unsigned long long a = keys[i], c = keys[l];
                    bool up = ((i & k) == 0);
                    if ((a < c) == up) { keys[i] = c; keys[l] = a; }
                }
            }
            __syncthreads();
        }
    for (int i = tid; i < K; i += 1024)
        outIdx[(size_t)b * K + i] = (int)(~(unsigned int)keys[i]);
}

// ---------------- gather bodies ----------------
__device__ __forceinline__ void dev_gatherW(const float* __restrict__ pw, const int* __restrict__ iidx,
                                            _Float16* __restrict__ Wh, _Float16* __restrict__ Wl,
                                            int p, int b, size_t bstride) {
    const float* row = pw + (size_t)p * NIN;
    const int* ix = iidx + (size_t)b * KIN;
    _Float16* wh = Wh + bstride + (size_t)p * KIN;
    _Float16* wl = Wl + bstride + (size_t)p * KIN;
    for (int j = threadIdx.x; j < KIN; j += 256) {
        float w = row[ix[j]];
        _Float16 h = (_Float16)w;
        wh[j] = h;
        wl[j] = (_Float16)(w - (float)h);
    }
}

__global__ void k_gatherSP(const _Float16* __restrict__ acts16, const int* __restrict__ pidx,
                           _Float16* __restrict__ sp) {
    int s = blockIdx.x, b = blockIdx.y;
    const _Float16* arow = acts16 + ((size_t)b * S_ + s) * NPROC;
    _Float16* orow = sp + ((size_t)b * S_ + s) * KPROC;
    const int* pi = pidx + (size_t)b * KPROC;
    for (int k = threadIdx.x; k < KPROC; k += 256) orow[k] = arow[pi[k]];
}

__global__ void k_gatherWoT(const _Float16* __restrict__ pout16, const int* __restrict__ pidx,
                            _Float16* __restrict__ woT) {
    __shared__ _Float16 t[64][65];
    int k0 = blockIdx.x * 64, d0 = blockIdx.y * 64, b = blockIdx.z;
    const int* pi = pidx + (size_t)b * KPROC;
    for (int i = threadIdx.x; i < 4096; i += 256) {
        int kk = i >> 6, dd = i & 63;
        t[kk][dd] = pout16[(size_t)pi[k0 + kk] * D_ + d0 + dd];
    }
    __syncthreads();
    for (int i = threadIdx.x; i < 4096; i += 256) {
        int dd = i >> 6, kk = i & 63;
        woT[((size_t)b * D_ + d0 + dd) * KPROC + k0 + kk] = t[kk][dd];
    }
}

// XOR-swizzle: LDS physical chunk s of row r holds global chunk s ^ ((r>>1)&3).
// Writer permutes global source per lane; reader XORs its chunk index.
// (chunk layout identical for every 64-row stage group since 64 % 8 == 0)

// ---------------- stage D body: sel_acts = gelu(x16 * (ph+pl)^T), 32x32x16 MFMA ----------------
// Block tile 256(M) x 128(N), 4 waves as 2x2, wave tile 128x64 (mi=4, nj=2).
// LDS bytes per MFMA drops 1.125KB -> 0.75KB vs the old 64x64 wave tile (LDS-BW-bound fix).
__device__ __forceinline__ void dev_gemmD(
    const _Float16* __restrict__ x16, const _Float16* __restrict__ ph, const _Float16* __restrict__ pl,
    const int* __restrict__ iidx, _Float16* __restrict__ a16,
    _Float16* tA, _Float16* tBh, _Float16* tBl, int bx, int by, int b)
{
    const int m0 = bx * 256, n0 = by * 128;
    const int tid = threadIdx.x, lane = tid & 63;
    const int wave = tid >> 6, wrow = wave >> 1, wcol = wave & 1;
    const int srow = tid >> 2, spart = tid & 3;
    const int spe = spart ^ ((srow >> 1) & 3);

    const _Float16* as0 = x16 + ((size_t)b * S_ + m0 + srow) * D_ + spe * 8;
    int r0 = iidx[(size_t)b * KIN + n0 + srow];
    int r1 = iidx[(size_t)b * KIN + n0 + srow + 64];
    const _Float16* bh0 = ph + (size_t)r0 * D_ + spe * 8;
    const _Float16* bh1 = ph + (size_t)r1 * D_ + spe * 8;
    const _Float16* bl0 = pl + (size_t)r0 * D_ + spe * 8;
    const _Float16* bl1 = pl + (size_t)r1 * D_ + spe * 8;

    v16f acc[4][2];
#pragma unroll
    for (int i = 0; i < 4; i++)
#pragma unroll
        for (int j = 0; j < 2; j++) acc[i][j] = (v16f)(0.0f);

    const int lrow = lane & 31, lhi = lane >> 5;
    const int swz = (lane >> 1) & 3;
    const int abase = (wrow * 128 + lrow) * 32;
    const int bbase = (wcol * 64 + lrow) * 32;

    for (int kt = 0; kt < D_; kt += 32) {
        __syncthreads();
        cp16(&tA[tid * 8],        as0 + kt);
        cp16(&tA[2048 + tid * 8], as0 + (size_t)64  * D_ + kt);
        cp16(&tA[4096 + tid * 8], as0 + (size_t)128 * D_ + kt);
        cp16(&tA[6144 + tid * 8], as0 + (size_t)192 * D_ + kt);
        cp16(&tBh[tid * 8],        bh0 + kt);
        cp16(&tBh[2048 + tid * 8], bh1 + kt);
        cp16(&tBl[tid * 8],        bl0 + kt);
        cp16(&tBl[2048 + tid * 8], bl1 + kt);
        asm volatile("s_waitcnt vmcnt(0)" ::: "memory");
        __syncthreads();
#pragma unroll
        for (int kw = 0; kw < 2; kw++) {
            const int ch = ((kw * 2 + lhi) ^ swz) * 8;
            v8h af[4], fh[2], fl[2];
#pragma unroll
            for (int mi = 0; mi < 4; mi++) af[mi] = *(const v8h*)&tA[abase + mi * 1024 + ch];
#pragma unroll
            for (int nj = 0; nj < 2; nj++) {
                fh[nj] = *(const v8h*)&tBh[bbase + nj * 1024 + ch];
                fl[nj] = *(const v8h*)&tBl[bbase + nj * 1024 + ch];
            }
#pragma unroll
            for (int mi = 0; mi < 4; mi++)
#pragma unroll
                for (int nj = 0; nj < 2; nj++) {
                    acc[mi][nj] = __builtin_amdgcn_mfma_f32_32x32x16_f16(af[mi], fh[nj], acc[mi][nj], 0, 0, 0);
                    acc[mi][nj] = __builtin_amdgcn_mfma_f32_32x32x16_f16(af[mi], fl[nj], acc[mi][nj], 0, 0, 0);
                }
        }
    }
#pragma unroll
    for (int mi = 0; mi < 4; mi++)
#pragma unroll
        for (int nj = 0; nj < 2; nj++)
#pragma unroll
            for (int r = 0; r < 16; r++) {
                int row = (r & 3) + 8 * (r >> 2) + 4 * lhi;
                float gv = geluf(acc[mi][nj][r]);
                a16[((size_t)b * S_ + m0 + wrow * 128 + mi * 32 + row) * (size_t)KIN
                    + n0 + wcol * 64 + nj * 32 + lrow] = (_Float16)gv;
            }
}

__global__ __launch_bounds__(256, 2) void k_gemmD(
    const _Float16* __restrict__ x16, const _Float16* __restrict__ ph, const _Float16* __restrict__ pl,
    const int* __restrict__ iidx, _Float16* __restrict__ a16)
{
    __shared__ _Float16 tA[8192], tBh[4096], tBl[4096];
    dev_gemmD(x16, ph, pl, iidx, a16, tA, tBh, tBl, blockIdx.x, blockIdx.y, blockIdx.z);
}

// fused: z<4 -> gemmD batch z; z>=4 -> gatherW block (overlaps MFMA-bound D with HBM-bound gather)
__global__ __launch_bounds__(256, 2) void k_fusedDW(
    const _Float16* __restrict__ x16, const _Float16* __restrict__ ph, const _Float16* __restrict__ pl,
    const int* __restrict__ iidx, _Float16* __restrict__ a16,
    const float* __restrict__ pw, _Float16* __restrict__ Wh, _Float16* __restrict__ Wl, size_t wstride)
{
    __shared__ _Float16 tA[8192], tBh[4096], tBl[4096];
    if (blockIdx.z >= 4) {
        int idx = (blockIdx.z - 4) * 256 + blockIdx.y * 8 + blockIdx.x;  // [0, 16384)
        int p = idx >> 2, b = idx & 3;
        dev_gatherW(pw, iidx, Wh, Wl, p, b, (size_t)b * wstride);
        return;
    }
    dev_gemmD(x16, ph, pl, iidx, a16, tA, tBh, tBl, blockIdx.x, blockIdx.y, blockIdx.z);
}

__global__ void k_gatherW(const float* __restrict__ pw, const int* __restrict__ iidx,
                          _Float16* __restrict__ Wh, _Float16* __restrict__ Wl,
                          int b_base, size_t wstride) {
    dev_gatherW(pw, iidx, Wh, Wl, blockIdx.x, b_base + blockIdx.y, (size_t)blockIdx.y * wstride);
}

// ---------------- stage E: proc_acts = gelu(a16 * (Wh+Wl)^T), 32x32x16, scores += col sums ----------------
__global__ __launch_bounds__(256, 2) void k_gemmE(
    const _Float16* __restrict__ a16, const _Float16* __restrict__ Wh, const _Float16* __restrict__ Wl,
    _Float16* __restrict__ acts16, double* __restrict__ scores, int b_base, size_t wstride)
{
    const int b = b_base + blockIdx.z;
    const int m0 = blockIdx.x * 256, n0 = blockIdx.y * 128;
    __shared__ _Float16 tA[8192], tBh[4096], tBl[4096];
    const int tid = threadIdx.x, lane = tid & 63;
    const int wave = tid >> 6, wrow = wave >> 1, wcol = wave & 1;
    const int srow = tid >> 2, spart = tid & 3;
    const int spe = spart ^ ((srow >> 1) & 3);

    const _Float16* as0 = a16 + ((size_t)b * S_ + m0 + srow) * (size_t)KIN + spe * 8;
    const _Float16* whB = Wh + (size_t)blockIdx.z * wstride;
    const _Float16* wlB = Wl + (size_t)blockIdx.z * wstride;
    const _Float16* bh0 = whB + (size_t)(n0 + srow) * KIN + spe * 8;
    const _Float16* bh1 = bh0 + (size_t)64 * KIN;
    const _Float16* bl0 = wlB + (size_t)(n0 + srow) * KIN + spe * 8;
    const _Float16* bl1 = bl0 + (size_t)64 * KIN;

    v16f acc[4][2];
#pragma unroll
    for (int i = 0; i < 4; i++)
#pragma unroll
        for (int j = 0; j < 2; j++) acc[i][j] = (v16f)(0.0f);

    const int lrow = lane & 31, lhi = lane >> 5;
    const int swz = (lane >> 1) & 3;
    const int abase = (wrow * 128 + lrow) * 32;
    const int bbase = (wcol * 64 + lrow) * 32;

    for (int kt = 0; kt < KIN; kt += 32) {
        __syncthreads();
        cp16(&tA[tid * 8],        as0 + kt);
        cp16(&tA[2048 + tid * 8], as0 + (size_t)64  * KIN + kt);
        cp16(&tA[4096 + tid * 8], as0 + (size_t)128 * KIN + kt);
        cp16(&tA[6144 + tid * 8], as0 + (size_t)192 * KIN + kt);
        cp16(&tBh[tid * 8],        bh0 + kt);
        cp16(&tBh[2048 + tid * 8], bh1 + kt);
        cp16(&tBl[tid * 8],        bl0 + kt);
        cp16(&tBl[2048 + tid * 8], bl1 + kt);
        asm volatile("s_waitcnt vmcnt(0)" ::: "memory");
        __syncthreads();
#pragma unroll
        for (int kw = 0; kw < 2; kw++) {
            const int ch = ((kw * 2 + lhi) ^ swz) * 8;
            v8h af[4], fh[2], fl[2];
#pragma unroll
            for (int mi = 0; mi < 4; mi++) af[mi] = *(const v8h*)&tA[abase + mi * 1024 + ch];
#pragma unroll
            for (int nj = 0; nj < 2; nj++) {
                fh[nj] = *(const v8h*)&tBh[bbase + nj * 1024 + ch];
                fl[nj] = *(const v8h*)&tBl[bbase + nj * 1024 + ch];
            }
#pragma unroll
            for (int mi = 0; mi < 4; mi++)
#pragma unroll
                for (int nj = 0; nj < 2; nj++) {
                    acc[mi][nj] = __builtin_amdgcn_mfma_f32_32x32x16_f16(af[mi], fh[nj], acc[mi][nj], 0, 0, 0);
                    acc[mi][nj] = __builtin_amdgcn_mfma_f32_32x32x16_f16(af[mi], fl[nj], acc[mi][nj], 0, 0, 0);
                }
        }
    }
    float psum[2] = {0.f, 0.f};
#pragma unroll
    for (int mi = 0; mi < 4; mi++)
#pragma unroll
        for (int nj = 0; nj < 2; nj++)
#pragma unroll
            for (int r = 0; r < 16; r++) {
                int row = (r & 3) + 8 * (r >> 2) + 4 * lhi;
                float gv = geluf(acc[mi][nj][r]);
                acts16[((size_t)b * S_ + m0 + wrow * 128 + mi * 32 + row) * (size_t)NPROC
                       + n0 + wcol * 64 + nj * 32 + lrow] = (_Float16)gv;
                psum[nj] += gv;
            }
#pragma unroll
    for (int nj = 0; nj < 2; nj++) {
        float s = psum[nj];
        s += __shfl_xor(s, 32, 64);
        if (lhi == 0)
            atomicAdd(&scores[(size_t)b * NPROC + n0 + wcol * 64 + nj * 32 + lrow], (double)s);
    }
}

// ---------------- stage F: out = sp * woT^T (plain f16, 32x32x16) ----------------
__global__ __launch_bounds__(256, 2) void k_gemmF(
    const _Float16* __restrict__ sp, const _Float16* __restrict__ woT, float* __restrict__ out)
{
    const int b = blockIdx.z;
    const int m0 = blockIdx.x * 256, n0 = blockIdx.y * 128;
    __shared__ _Float16 tA[8192], tB[4096];
    const int tid = threadIdx.x, lane = tid & 63;
    const int wave = tid >> 6, wrow = wave >> 1, wcol = wave & 1;
    const int srow = tid >> 2, spart = tid & 3;
    const int spe = spart ^ ((srow >> 1) & 3);

    const _Float16* as0 = sp + ((size_t)b * S_ + m0 + srow) * (size_t)KPROC + spe * 8;
    const _Float16* bs0 = woT + ((size_t)b * D_ + n0 + srow) * (size_t)KPROC + spe * 8;
    const _Float16* bs1 = bs0 + (size_t)64 * KPROC;

    v16f acc[4][2];
#pragma unroll
    for (int i = 0; i < 4; i++)
#pragma unroll
        for (int j = 0; j < 2; j++) acc[i][j] = (v16f)(0.0f);

    const int lrow = lane & 31, lhi = lane >> 5;
    const int swz = (lane >> 1) & 3;
    const int abase = (wrow * 128 + lrow) * 32;
    const int bbase = (wcol * 64 + lrow) * 32;

    for (int kt = 0; kt < KPROC; kt += 32) {
        __syncthreads();
        cp16(&tA[tid * 8],        as0 + kt);
        cp16(&tA[2048 + tid * 8], as0 + (size_t)64  * KPROC + kt);
        cp16(&tA[4096 + tid * 8], as0 + (size_t)128 * KPROC + kt);
        cp16(&tA[6144 + tid * 8], as0 + (size_t)192 * KPROC + kt);
        cp16(&tB[tid * 8],        bs0 + kt);
        cp16(&tB[2048 + tid * 8], bs1 + kt);
        asm volatile("s_waitcnt vmcnt(0)" ::: "memory");
        __syncthreads();
#pragma unroll
        for (int kw = 0; kw < 2; kw++) {
            const int ch = ((kw * 2 + lhi) ^ swz) * 8;
            v8h af[4], bf[2];
#pragma unroll
            for (int mi = 0; mi < 4; mi++) af[mi] = *(const v8h*)&tA[abase + mi * 1024 + ch];
#pragma unroll
            for (int nj = 0; nj < 2; nj++) bf[nj] = *(const v8h*)&tB[bbase + nj * 1024 + ch];
#pragma unroll
            for (int mi = 0; mi < 4; mi++)
#pragma unroll
                for (int nj = 0; nj < 2; nj++)
                    acc[mi][nj] = __builtin_amdgcn_mfma_f32_32x32x16_f16(af[mi], bf[nj], acc[mi][nj], 0, 0, 0);
        }
    }
#pragma unroll
    for (int mi = 0; mi < 4; mi++)
#pragma unroll
        for (int nj = 0; nj < 2; nj++)
#pragma unroll
            for (int r = 0; r < 16; r++) {
                int row = (r & 3) + 8 * (r >> 2) + 4 * lhi;
                out[((size_t)b * S_ + m0 + wrow * 128 + mi * 32 + row) * (size_t)D_
                    + n0 + wcol * 64 + nj * 32 + lrow] = acc[mi][nj][r];
            }
}

// ---------------- host ----------------
extern "C" void kernel_launch(void* const* d_in, const int* in_sizes, int n_in,
                              void* d_out, int out_size, void* d_ws, size_t ws_size,
                              hipStream_t stream) {
    const float* x    = (const float*)d_in[0];
    const float* W1   = (const float*)d_in[1];
    const float* b1   = (const float*)d_in[2];
    const float* lng  = (const float*)d_in[3];
    const float* lnb  = (const float*)d_in[4];
    const float* W2   = (const float*)d_in[5];
    const float* b2   = (const float*)d_in[6];
    const float* keys = (const float*)d_in[7];
    const float* patt = (const float*)d_in[8];
    const float* pw   = (const float*)d_in[9];
    const float* pout = (const float*)d_in[10];
    (void)in_sizes; (void)n_in; (void)out_size;

    char* w = (char*)d_ws;
    size_t off = 0;
    auto alloc = [&](size_t bytes) -> void* {
        void* p = w + off;
        off += (bytes + 255) & ~(size_t)255;
        return p;
    };
    double* gc64   = (double*)alloc((size_t)B_ * D_ * 8);
    float*  pmax   = (float*) alloc((size_t)B_ * 16 * D_ * 4);
    double* logits = (double*)alloc((size_t)B_ * NIN * 8);
    double* scores = (double*)alloc((size_t)B_ * NPROC * 8);
    double* hpre   = (double*)alloc((size_t)B_ * DR2 * 8);
    double* qs     = (double*)alloc((size_t)B_ * DR * 8);
    int*    iidx   = (int*)   alloc((size_t)B_ * KIN * 4);
    int*    pidx   = (int*)   alloc((size_t)B_ * KPROC * 4);
    _Float16* a16    = (_Float16*)alloc((size_t)B_ * S_ * KIN * 2);    // 67 MB
    _Float16* acts16 = (_Float16*)alloc((size_t)B_ * S_ * NPROC * 2);  // 67 MB
    _Float16* pout16 = (_Float16*)alloc((size_t)NPROC * D_ * 2);       // 8.4 MB
    char* u1 = (char*)alloc((size_t)67108864);
    _Float16* x16 = (_Float16*)u1;
    _Float16* ph  = (_Float16*)(u1 + 16777216);
    _Float16* pl  = (_Float16*)(u1 + 33554432);
    _Float16* WhT = (_Float16*)u1;               // thin path, one batch
    _Float16* WlT = (_Float16*)(u1 + 33554432);
    _Float16* sp  = (_Float16*)u1;
    _Float16* woT = (_Float16*)(u1 + 33554432);

    const size_t WSTRIDE = (size_t)NPROC * KIN;
    size_t off_before_fat = off;
    _Float16* WhA = (_Float16*)alloc((size_t)B_ * WSTRIDE * 2);
    _Float16* WlA = (_Float16*)alloc((size_t)B_ * WSTRIDE * 2);
    bool fat = (off <= ws_size);
    if (!fat) off = off_before_fat;

    hipMemsetAsync(scores, 0, (size_t)B_ * NPROC * 8, stream);

    k_conv_x16 <<<dim3((B_ * S_ * D_ / 4 + 255) / 256), 256, 0, stream>>>(x, x16, B_ * S_ * D_ / 4);
    k_conv_split<<<dim3((NIN * D_ + 255) / 256), 256, 0, stream>>>(patt, ph, pl, NIN * D_);
    k_conv_x16 <<<dim3((NPROC * D_ / 4 + 255) / 256), 256, 0, stream>>>(pout, pout16, NPROC * D_ / 4);

    k_max1<<<dim3(4, 16, 4), 256, 0, stream>>>(x, pmax);
    k_max2<<<dim3(4, 4), 256, 0, stream>>>(pmax, gc64);
    k_router1<<<dim3(128, 4), 256, 0, stream>>>(gc64, W1, b1, hpre);
    k_router2<<<dim3(4), 512, 0, stream>>>(hpre, lng, lnb, W2, b2, qs);
    k_router3<<<dim3(2048, 4), 256, 0, stream>>>(qs, keys, logits);
    k_topk<NIN, KIN><<<dim3(4), 1024, 0, stream>>>(logits, iidx);

    if (fat) {
        // one launch: D (z<4, MFMA-bound, dispatched first) + all-batch gatherW (z>=4, HBM-bound) overlap
        // gemmD grid is now 8x32 per batch; gather units = 16384 = 64 z-slices of 256 blocks
        k_fusedDW<<<dim3(8, 32, 68), 256, 0, stream>>>(x16, ph, pl, iidx, a16, pw, WhA, WlA, WSTRIDE);
        k_gemmE<<<dim3(8, 32, 4), 256, 0, stream>>>(a16, WhA, WlA, acts16, scores, 0, WSTRIDE);
    } else {
        k_gemmD<<<dim3(8, 32, 4), 256, 0, stream>>>(x16, ph, pl, iidx, a16);
        for (int b = 0; b < 4; b++) {
            k_gatherW<<<dim3(NPROC, 1), 256, 0, stream>>>(pw, iidx, WhT, WlT, b, 0);
            k_gemmE<<<dim3(8, 32, 1), 256, 0, stream>>>(a16, WhT, WlT, acts16, scores, b, 0);
        }
    }

    k_topk<NPROC, KPROC><<<dim3(4), 1024, 0, stream>>>(scores, pidx);
    k_gatherSP<<<dim3(S_, 4), 256, 0, stream>>>(acts16, pidx, sp);
    k_gatherWoT<<<dim3(KPROC / 64, D_ / 64, 4), 256, 0, stream>>>(pout16, pidx, woT);
    k_gemmF<<<dim3(8, 8, 4), 256, 0, stream>>>(sp, woT, (float*)d_out);
}

// Round 2
// 1573.512 us; speedup vs baseline: 1.0434x; 1.0434x over previous
//
#include <hip/hip_runtime.h>
#include <cstdint>

#define B_    4
#define S_    2048
#define D_    1024
#define NIN   8192
#define NPROC 4096
#define DR    256
#define DR2   512
#define KIN   4096
#define KPROC 2048

typedef _Float16 v8h  __attribute__((ext_vector_type(8)));
typedef _Float16 v4h  __attribute__((ext_vector_type(4)));
typedef float    v4f  __attribute__((ext_vector_type(4)));
typedef float    v16f __attribute__((ext_vector_type(16)));

__device__ __forceinline__ float geluf(float v) {
    return 0.5f * v * (1.0f + erff(v * 0.70710678f));
}

// async global->LDS, 16B per lane. LDS dest semantics: wave-uniform base + lane*16.
__device__ __forceinline__ void cp16(void* lds, const void* g) {
    __builtin_amdgcn_global_load_lds(
        (const __attribute__((address_space(1))) unsigned int*)g,
        (__attribute__((address_space(3))) unsigned int*)lds, 16, 0, 0);
}

// ---------------- converts ----------------
__global__ void k_conv_x16(const float* __restrict__ x, _Float16* __restrict__ x16, int n4) {
    int i = blockIdx.x * 256 + threadIdx.x;
    if (i < n4) {
        float4 v = ((const float4*)x)[i];
        v4h h = { (_Float16)v.x, (_Float16)v.y, (_Float16)v.z, (_Float16)v.w };
        ((v4h*)x16)[i] = h;
    }
}

__global__ void k_conv_split(const float* __restrict__ p, _Float16* __restrict__ ph,
                             _Float16* __restrict__ pl, int n) {
    int i = blockIdx.x * 256 + threadIdx.x;
    if (i < n) {
        float v = p[i];
        _Float16 h = (_Float16)v;
        ph[i] = h;
        pl[i] = (_Float16)(v - (float)h);
    }
}

// ---------------- gc = max over s ----------------
__global__ void k_max1(const float* __restrict__ x, float* __restrict__ pmax) {
    int d = blockIdx.x * 256 + threadIdx.x;
    int chunk = blockIdx.y;
    int b = blockIdx.z;
    const float* base = x + ((size_t)b * S_ + chunk * 128) * D_ + d;
    float m = -3.4e38f;
    for (int s = 0; s < 128; s++) m = fmaxf(m, base[(size_t)s * D_]);
    pmax[((size_t)b * 16 + chunk) * D_ + d] = m;
}

__global__ void k_max2(const float* __restrict__ pmax, double* __restrict__ gc64) {
    int d = blockIdx.x * 256 + threadIdx.x;
    int b = blockIdx.y;
    float m = -3.4e38f;
    for (int c = 0; c < 16; c++) m = fmaxf(m, pmax[((size_t)b * 16 + c) * D_ + d]);
    gc64[(size_t)b * D_ + d] = (double)m;
}

// ---------------- router (fp64) ----------------
__global__ __launch_bounds__(256) void k_router1(
    const double* __restrict__ gc64, const float* __restrict__ W1, const float* __restrict__ b1,
    double* __restrict__ hpre)
{
    int wave = threadIdx.x >> 6, lane = threadIdx.x & 63;
    int j = blockIdx.x * 4 + wave;
    int b = blockIdx.y;
    const double* g = gc64 + (size_t)b * D_;
    const float* w = W1 + (size_t)j * D_;
    double acc = 0.0;
    for (int d = lane; d < D_; d += 64) acc += g[d] * (double)w[d];
#pragma unroll
    for (int o = 32; o > 0; o >>= 1) acc += __shfl_xor(acc, o, 64);
    if (lane == 0) {
        double z = acc + (double)b1[j];
        hpre[(size_t)b * DR2 + j] = 0.5 * z * (1.0 + erf(z * 0.7071067811865475244));
    }
}

__global__ __launch_bounds__(512) void k_router2(
    const double* __restrict__ hpre, const float* __restrict__ lng, const float* __restrict__ lnb,
    const float* __restrict__ W2, const float* __restrict__ b2, double* __restrict__ qs)
{
    __shared__ double sh[DR2];
    __shared__ double red[DR2];
    int b = blockIdx.x, j = threadIdx.x;
    double ge = hpre[(size_t)b * DR2 + j];
    sh[j] = ge; red[j] = ge;
    __syncthreads();
    for (int s = 256; s > 0; s >>= 1) { if (j < s) red[j] += red[j + s]; __syncthreads(); }
    double mu = red[0] / 512.0;
    __syncthreads();
    double dv = ge - mu;
    red[j] = dv * dv;
    __syncthreads();
    for (int s = 256; s > 0; s >>= 1) { if (j < s) red[j] += red[j + s]; __syncthreads(); }
    double rs = 1.0 / sqrt(red[0] / 512.0 + 1e-5);
    __syncthreads();
    sh[j] = dv * rs * (double)lng[j] + (double)lnb[j];
    __syncthreads();
    if (j < DR) {
        double q = (double)b2[j];
        const float* w2r = W2 + (size_t)j * DR2;
        for (int t = 0; t < DR2; t++) q += sh[t] * (double)w2r[t];
        qs[(size_t)b * DR + j] = q;
    }
}

__global__ __launch_bounds__(256) void k_router3(
    const double* __restrict__ qs, const float* __restrict__ keys, double* __restrict__ logits)
{
    int wave = threadIdx.x >> 6, lane = threadIdx.x & 63;
    int n = blockIdx.x * 4 + wave;
    int b = blockIdx.y;
    const double* q = qs + (size_t)b * DR;
    const float* kr = keys + (size_t)n * DR;
    double acc = 0.0;
#pragma unroll
    for (int t = 0; t < 4; t++) {
        int d = lane + t * 64;
        acc += q[d] * (double)kr[d];
    }
#pragma unroll
    for (int o = 32; o > 0; o >>= 1) acc += __shfl_xor(acc, o, 64);
    if (lane == 0) logits[(size_t)b * NIN + n] = acc * 0.0625;
}

// ---------------- top-k ----------------
template<int N, int K>
__global__ __launch_bounds__(1024) void k_topk(const double* __restrict__ vals, int* __restrict__ outIdx) {
    __shared__ unsigned long long keys[N];
    int b = blockIdx.x, tid = threadIdx.x;
    for (int i = tid; i < N; i += 1024) {
        float v = (float)vals[(size_t)b * N + i];
        unsigned int u = __float_as_uint(v);
        u = (u & 0x80000000u) ? ~u : (u | 0x80000000u);
        keys[i] = ((unsigned long long)u << 32) | (unsigned int)(~i);
    }
    __syncthreads();
    for (int k = 2; k <= N; k <<= 1)
        for (int j = k >> 1; j > 0; j >>= 1) {
            for (int i = tid; i < N; i += 1024) {
                int l = i ^ j;
                if (l > i) {
                    unsigned long long a = keys[i], c = keys[l];
                    bool up = ((i & k) == 0);
                    if ((a < c) == up) { keys[i] = c; keys[l] = a; }
                }
            }
            __syncthreads();
        }
    for (int i = tid; i < K; i += 1024)
        outIdx[(size_t)b * K + i] = (int)(~(unsigned int)keys[i]);
}

// ---------------- gather bodies ----------------
__device__ __forceinline__ void dev_gatherW(const float* __restrict__ pw, const int* __restrict__ iidx,
                                            _Float16* __restrict__ Wh, _Float16* __restrict__ Wl,
                                            int p, int b, size_t bstride) {
    const float* row = pw + (size_t)p * NIN;
    const int* ix = iidx + (size_t)b * KIN;
    _Float16* wh = Wh + bstride + (size_t)p * KIN;
    _Float16* wl = Wl + bstride + (size_t)p * KIN;
    for (int j = threadIdx.x; j < KIN; j += 256) {
        float w = row[ix[j]];
        _Float16 h = (_Float16)w;
        wh[j] = h;
        wl[j] = (_Float16)(w - (float)h);
    }
}

__global__ void k_gatherSP(const _Float16* __restrict__ acts16, const int* __restrict__ pidx,
                           _Float16* __restrict__ sp) {
    int s = blockIdx.x, b = blockIdx.y;
    const _Float16* arow = acts16 + ((size_t)b * S_ + s) * NPROC;
    _Float16* orow = sp + ((size_t)b * S_ + s) * KPROC;
    const int* pi = pidx + (size_t)b * KPROC;
    for (int k = threadIdx.x; k < KPROC; k += 256) orow[k] = arow[pi[k]];
}

__global__ void k_gatherWoT(const _Float16* __restrict__ pout16, const int* __restrict__ pidx,
                            _Float16* __restrict__ woT) {
    __shared__ _Float16 t[64][65];
    int k0 = blockIdx.x * 64, d0 = blockIdx.y * 64, b = blockIdx.z;
    const int* pi = pidx + (size_t)b * KPROC;
    for (int i = threadIdx.x; i < 4096; i += 256) {
        int kk = i >> 6, dd = i & 63;
        t[kk][dd] = pout16[(size_t)pi[k0 + kk] * D_ + d0 + dd];
    }
    __syncthreads();
    for (int i = threadIdx.x; i < 4096; i += 256) {
        int dd = i >> 6, kk = i & 63;
        woT[((size_t)b * D_ + d0 + dd) * KPROC + k0 + kk] = t[kk][dd];
    }
}

// XOR-swizzle: LDS physical chunk s of row r holds global chunk s ^ ((r>>1)&3).
// Writer permutes global source per lane; reader XORs its chunk index.

// ---------------- stage D body: sel_acts = gelu(x16 * (ph+pl)^T), 32x32x16 MFMA ----------------
// 128x128 block tile, 2x2 waves, 64x64 wave tile (round-0 geometry: 3 blocks/CU).
// 2-phase LDS double-buffer: STAGE(t+1) -> ds_read/MFMA(t) -> vmcnt(0) -> ONE barrier.
// Loads for t+1 hide under the compute phase of t (was: serial drain per K-step).
__device__ __forceinline__ void dev_gemmD(
    const _Float16* __restrict__ x16, const _Float16* __restrict__ ph, const _Float16* __restrict__ pl,
    const int* __restrict__ iidx, _Float16* __restrict__ a16,
    _Float16* tA, _Float16* tBh, _Float16* tBl, int bx, int by, int b)
{
    const int m0 = bx * 128, n0 = by * 128;
    const int tid = threadIdx.x, lane = tid & 63;
    const int wave = tid >> 6, wrow = wave >> 1, wcol = wave & 1;
    const int srow = tid >> 2, spart = tid & 3;
    const int spe = spart ^ ((srow >> 1) & 3);

    const _Float16* as0 = x16 + ((size_t)b * S_ + m0 + srow) * D_ + spe * 8;
    const _Float16* as1 = as0 + (size_t)64 * D_;
    int r0 = iidx[(size_t)b * KIN + n0 + srow];
    int r1 = iidx[(size_t)b * KIN + n0 + srow + 64];
    const _Float16* bh0 = ph + (size_t)r0 * D_ + spe * 8;
    const _Float16* bh1 = ph + (size_t)r1 * D_ + spe * 8;
    const _Float16* bl0 = pl + (size_t)r0 * D_ + spe * 8;
    const _Float16* bl1 = pl + (size_t)r1 * D_ + spe * 8;

    v16f acc[2][2];
#pragma unroll
    for (int i = 0; i < 2; i++)
#pragma unroll
        for (int j = 0; j < 2; j++) acc[i][j] = (v16f)(0.0f);

    const int lrow = lane & 31, lhi = lane >> 5;
    const int swz = (lane >> 1) & 3;
    const int abase = (wrow * 64 + lrow) * 32;
    const int bbase = (wcol * 64 + lrow) * 32;

    // prologue: stage tile 0 into buffer 0
    cp16(&tA[tid * 8], as0);
    cp16(&tA[2048 + tid * 8], as1);
    cp16(&tBh[tid * 8], bh0);
    cp16(&tBh[2048 + tid * 8], bh1);
    cp16(&tBl[tid * 8], bl0);
    cp16(&tBl[2048 + tid * 8], bl1);
    asm volatile("s_waitcnt vmcnt(0)" ::: "memory");
    __syncthreads();

    for (int kt = 0; kt < D_; kt += 32) {
        const int cur = (kt >> 5) & 1;
        const int o = cur * 4096;
        if (kt + 32 < D_) {
            const int on = (cur ^ 1) * 4096;
            const int kn = kt + 32;
            cp16(&tA[on + tid * 8], as0 + kn);
            cp16(&tA[on + 2048 + tid * 8], as1 + kn);
            cp16(&tBh[on + tid * 8], bh0 + kn);
            cp16(&tBh[on + 2048 + tid * 8], bh1 + kn);
            cp16(&tBl[on + tid * 8], bl0 + kn);
            cp16(&tBl[on + 2048 + tid * 8], bl1 + kn);
        }
        v8h af[2][2], fh[2][2], fl[2][2];
#pragma unroll
        for (int kw = 0; kw < 2; kw++) {
            const int ch = ((kw * 2 + lhi) ^ swz) * 8;
#pragma unroll
            for (int mi = 0; mi < 2; mi++) af[mi][kw] = *(const v8h*)&tA[o + abase + mi * 1024 + ch];
#pragma unroll
            for (int nj = 0; nj < 2; nj++) {
                fh[nj][kw] = *(const v8h*)&tBh[o + bbase + nj * 1024 + ch];
                fl[nj][kw] = *(const v8h*)&tBl[o + bbase + nj * 1024 + ch];
            }
        }
#pragma unroll
        for (int kw = 0; kw < 2; kw++)
#pragma unroll
            for (int mi = 0; mi < 2; mi++)
#pragma unroll
                for (int nj = 0; nj < 2; nj++) {
                    acc[mi][nj] = __builtin_amdgcn_mfma_f32_32x32x16_f16(af[mi][kw], fh[nj][kw], acc[mi][nj], 0, 0, 0);
                    acc[mi][nj] = __builtin_amdgcn_mfma_f32_32x32x16_f16(af[mi][kw], fl[nj][kw], acc[mi][nj], 0, 0, 0);
                }
        asm volatile("s_waitcnt vmcnt(0)" ::: "memory");
        __syncthreads();
    }
#pragma unroll
    for (int mi = 0; mi < 2; mi++)
#pragma unroll
        for (int nj = 0; nj < 2; nj++)
#pragma unroll
            for (int r = 0; r < 16; r++) {
                int row = (r & 3) + 8 * (r >> 2) + 4 * lhi;
                float gv = geluf(acc[mi][nj][r]);
                a16[((size_t)b * S_ + m0 + wrow * 64 + mi * 32 + row) * (size_t)KIN
                    + n0 + wcol * 64 + nj * 32 + lrow] = (_Float16)gv;
            }
}

__global__ __launch_bounds__(256, 3) void k_gemmD(
    const _Float16* __restrict__ x16, const _Float16* __restrict__ ph, const _Float16* __restrict__ pl,
    const int* __restrict__ iidx, _Float16* __restrict__ a16)
{
    __shared__ _Float16 tA[8192], tBh[8192], tBl[8192];
    dev_gemmD(x16, ph, pl, iidx, a16, tA, tBh, tBl, blockIdx.x, blockIdx.y, blockIdx.z);
}

// fused: z<4 -> gemmD batch z; z>=4 -> gatherW block (overlaps MFMA-bound D with HBM-bound gather)
__global__ __launch_bounds__(256, 3) void k_fusedDW(
    const _Float16* __restrict__ x16, const _Float16* __restrict__ ph, const _Float16* __restrict__ pl,
    const int* __restrict__ iidx, _Float16* __restrict__ a16,
    const float* __restrict__ pw, _Float16* __restrict__ Wh, _Float16* __restrict__ Wl, size_t wstride)
{
    __shared__ _Float16 tA[8192], tBh[8192], tBl[8192];
    if (blockIdx.z >= 4) {
        int idx = (blockIdx.z - 4) * 512 + blockIdx.y * 16 + blockIdx.x;  // [0, 16384)
        int p = idx >> 2, b = idx & 3;
        dev_gatherW(pw, iidx, Wh, Wl, p, b, (size_t)b * wstride);
        return;
    }
    dev_gemmD(x16, ph, pl, iidx, a16, tA, tBh, tBl, blockIdx.x, blockIdx.y, blockIdx.z);
}

__global__ void k_gatherW(const float* __restrict__ pw, const int* __restrict__ iidx,
                          _Float16* __restrict__ Wh, _Float16* __restrict__ Wl,
                          int b_base, size_t wstride) {
    dev_gatherW(pw, iidx, Wh, Wl, blockIdx.x, b_base + blockIdx.y, (size_t)blockIdx.y * wstride);
}

// ---------------- stage E: proc_acts = gelu(a16 * (Wh+Wl)^T), 32x32x16, scores += col sums ----------------
__global__ __launch_bounds__(256, 3) void k_gemmE(
    const _Float16* __restrict__ a16, const _Float16* __restrict__ Wh, const _Float16* __restrict__ Wl,
    _Float16* __restrict__ acts16, double* __restrict__ scores, int b_base, size_t wstride)
{
    const int b = b_base + blockIdx.z;
    const int m0 = blockIdx.x * 128, n0 = blockIdx.y * 128;
    __shared__ _Float16 tA[8192], tBh[8192], tBl[8192];
    const int tid = threadIdx.x, lane = tid & 63;
    const int wave = tid >> 6, wrow = wave >> 1, wcol = wave & 1;
    const int srow = tid >> 2, spart = tid & 3;
    const int spe = spart ^ ((srow >> 1) & 3);

    const _Float16* as0 = a16 + ((size_t)b * S_ + m0 + srow) * (size_t)KIN + spe * 8;
    const _Float16* as1 = as0 + (size_t)64 * KIN;
    const _Float16* whB = Wh + (size_t)blockIdx.z * wstride;
    const _Float16* wlB = Wl + (size_t)blockIdx.z * wstride;
    const _Float16* bh0 = whB + (size_t)(n0 + srow) * KIN + spe * 8;
    const _Float16* bh1 = bh0 + (size_t)64 * KIN;
    const _Float16* bl0 = wlB + (size_t)(n0 + srow) * KIN + spe * 8;
    const _Float16* bl1 = bl0 + (size_t)64 * KIN;

    v16f acc[2][2];
#pragma unroll
    for (int i = 0; i < 2; i++)
#pragma unroll
        for (int j = 0; j < 2; j++) acc[i][j] = (v16f)(0.0f);

    const int lrow = lane & 31, lhi = lane >> 5;
    const int swz = (lane >> 1) & 3;
    const int abase = (wrow * 64 + lrow) * 32;
    const int bbase = (wcol * 64 + lrow) * 32;

    cp16(&tA[tid * 8], as0);
    cp16(&tA[2048 + tid * 8], as1);
    cp16(&tBh[tid * 8], bh0);
    cp16(&tBh[2048 + tid * 8], bh1);
    cp16(&tBl[tid * 8], bl0);
    cp16(&tBl[2048 + tid * 8], bl1);
    asm volatile("s_waitcnt vmcnt(0)" ::: "memory");
    __syncthreads();

    for (int kt = 0; kt < KIN; kt += 32) {
        const int cur = (kt >> 5) & 1;
        const int o = cur * 4096;
        if (kt + 32 < KIN) {
            const int on = (cur ^ 1) * 4096;
            const int kn = kt + 32;
            cp16(&tA[on + tid * 8], as0 + kn);
            cp16(&tA[on + 2048 + tid * 8], as1 + kn);
            cp16(&tBh[on + tid * 8], bh0 + kn);
            cp16(&tBh[on + 2048 + tid * 8], bh1 + kn);
            cp16(&tBl[on + tid * 8], bl0 + kn);
            cp16(&tBl[on + 2048 + tid * 8], bl1 + kn);
        }
        v8h af[2][2], fh[2][2], fl[2][2];
#pragma unroll
        for (int kw = 0; kw < 2; kw++) {
            const int ch = ((kw * 2 + lhi) ^ swz) * 8;
#pragma unroll
            for (int mi = 0; mi < 2; mi++) af[mi][kw] = *(const v8h*)&tA[o + abase + mi * 1024 + ch];
#pragma unroll
            for (int nj = 0; nj < 2; nj++) {
                fh[nj][kw] = *(const v8h*)&tBh[o + bbase + nj * 1024 + ch];
                fl[nj][kw] = *(const v8h*)&tBl[o + bbase + nj * 1024 + ch];
            }
        }
#pragma unroll
        for (int kw = 0; kw < 2; kw++)
#pragma unroll
            for (int mi = 0; mi < 2; mi++)
#pragma unroll
                for (int nj = 0; nj < 2; nj++) {
                    acc[mi][nj] = __builtin_amdgcn_mfma_f32_32x32x16_f16(af[mi][kw], fh[nj][kw], acc[mi][nj], 0, 0, 0);
                    acc[mi][nj] = __builtin_amdgcn_mfma_f32_32x32x16_f16(af[mi][kw], fl[nj][kw], acc[mi][nj], 0, 0, 0);
                }
        asm volatile("s_waitcnt vmcnt(0)" ::: "memory");
        __syncthreads();
    }
    float psum[2] = {0.f, 0.f};
#pragma unroll
    for (int mi = 0; mi < 2; mi++)
#pragma unroll
        for (int nj = 0; nj < 2; nj++)
#pragma unroll
            for (int r = 0; r < 16; r++) {
                int row = (r & 3) + 8 * (r >> 2) + 4 * lhi;
                float gv = geluf(acc[mi][nj][r]);
                acts16[((size_t)b * S_ + m0 + wrow * 64 + mi * 32 + row) * (size_t)NPROC
                       + n0 + wcol * 64 + nj * 32 + lrow] = (_Float16)gv;
                psum[nj] += gv;
            }
#pragma unroll
    for (int nj = 0; nj < 2; nj++) {
        float s = psum[nj];
        s += __shfl_xor(s, 32, 64);
        if (lhi == 0)
            atomicAdd(&scores[(size_t)b * NPROC + n0 + wcol * 64 + nj * 32 + lrow], (double)s);
    }
}

// ---------------- stage F: out = sp * woT^T (plain f16, 32x32x16) ----------------
__global__ __launch_bounds__(256, 3) void k_gemmF(
    const _Float16* __restrict__ sp, const _Float16* __restrict__ woT, float* __restrict__ out)
{
    const int b = blockIdx.z;
    const int m0 = blockIdx.x * 128, n0 = blockIdx.y * 128;
    __shared__ _Float16 tA[8192], tB[8192];
    const int tid = threadIdx.x, lane = tid & 63;
    const int wave = tid >> 6, wrow = wave >> 1, wcol = wave & 1;
    const int srow = tid >> 2, spart = tid & 3;
    const int spe = spart ^ ((srow >> 1) & 3);

    const _Float16* as0 = sp + ((size_t)b * S_ + m0 + srow) * (size_t)KPROC + spe * 8;
    const _Float16* as1 = as0 + (size_t)64 * KPROC;
    const _Float16* bs0 = woT + ((size_t)b * D_ + n0 + srow) * (size_t)KPROC + spe * 8;
    const _Float16* bs1 = bs0 + (size_t)64 * KPROC;

    v16f acc[2][2];
#pragma unroll
    for (int i = 0; i < 2; i++)
#pragma unroll
        for (int j = 0; j < 2; j++) acc[i][j] = (v16f)(0.0f);

    const int lrow = lane & 31, lhi = lane >> 5;
    const int swz = (lane >> 1) & 3;
    const int abase = (wrow * 64 + lrow) * 32;
    const int bbase = (wcol * 64 + lrow) * 32;

    cp16(&tA[tid * 8], as0);
    cp16(&tA[2048 + tid * 8], as1);
    cp16(&tB[tid * 8], bs0);
    cp16(&tB[2048 + tid * 8], bs1);
    asm volatile("s_waitcnt vmcnt(0)" ::: "memory");
    __syncthreads();

    for (int kt = 0; kt < KPROC; kt += 32) {
        const int cur = (kt >> 5) & 1;
        const int o = cur * 4096;
        if (kt + 32 < KPROC) {
            const int on = (cur ^ 1) * 4096;
            const int kn = kt + 32;
            cp16(&tA[on + tid * 8], as0 + kn);
            cp16(&tA[on + 2048 + tid * 8], as1 + kn);
            cp16(&tB[on + tid * 8], bs0 + kn);
            cp16(&tB[on + 2048 + tid * 8], bs1 + kn);
        }
        v8h af[2][2], bf[2][2];
#pragma unroll
        for (int kw = 0; kw < 2; kw++) {
            const int ch = ((kw * 2 + lhi) ^ swz) * 8;
#pragma unroll
            for (int mi = 0; mi < 2; mi++) af[mi][kw] = *(const v8h*)&tA[o + abase + mi * 1024 + ch];
#pragma unroll
            for (int nj = 0; nj < 2; nj++) bf[nj][kw] = *(const v8h*)&tB[o + bbase + nj * 1024 + ch];
        }
#pragma unroll
        for (int kw = 0; kw < 2; kw++)
#pragma unroll
            for (int mi = 0; mi < 2; mi++)
#pragma unroll
                for (int nj = 0; nj < 2; nj++)
                    acc[mi][nj] = __builtin_amdgcn_mfma_f32_32x32x16_f16(af[mi][kw], bf[nj][kw], acc[mi][nj], 0, 0, 0);
        asm volatile("s_waitcnt vmcnt(0)" ::: "memory");
        __syncthreads();
    }
#pragma unroll
    for (int mi = 0; mi < 2; mi++)
#pragma unroll
        for (int nj = 0; nj < 2; nj++)
#pragma unroll
            for (int r = 0; r < 16; r++) {
                int row = (r & 3) + 8 * (r >> 2) + 4 * lhi;
                out[((size_t)b * S_ + m0 + wrow * 64 + mi * 32 + row) * (size_t)D_
                    + n0 + wcol * 64 + nj * 32 + lrow] = acc[mi][nj][r];
            }
}

// ---------------- host ----------------
extern "C" void kernel_launch(void* const* d_in, const int* in_sizes, int n_in,
                              void* d_out, int out_size, void* d_ws, size_t ws_size,
                              hipStream_t stream) {
    const float* x    = (const float*)d_in[0];
    const float* W1   = (const float*)d_in[1];
    const float* b1   = (const float*)d_in[2];
    const float* lng  = (const float*)d_in[3];
    const float* lnb  = (const float*)d_in[4];
    const float* W2   = (const float*)d_in[5];
    const float* b2   = (const float*)d_in[6];
    const float* keys = (const float*)d_in[7];
    const float* patt = (const float*)d_in[8];
    const float* pw   = (const float*)d_in[9];
    const float* pout = (const float*)d_in[10];
    (void)in_sizes; (void)n_in; (void)out_size;

    char* w = (char*)d_ws;
    size_t off = 0;
    auto alloc = [&](size_t bytes) -> void* {
        void* p = w + off;
        off += (bytes + 255) & ~(size_t)255;
        return p;
    };
    double* gc64   = (double*)alloc((size_t)B_ * D_ * 8);
    float*  pmax   = (float*) alloc((size_t)B_ * 16 * D_ * 4);
    double* logits = (double*)alloc((size_t)B_ * NIN * 8);
    double* scores = (double*)alloc((size_t)B_ * NPROC * 8);
    double* hpre   = (double*)alloc((size_t)B_ * DR2 * 8);
    double* qs     = (double*)alloc((size_t)B_ * DR * 8);
    int*    iidx   = (int*)   alloc((size_t)B_ * KIN * 4);
    int*    pidx   = (int*)   alloc((size_t)B_ * KPROC * 4);
    _Float16* a16    = (_Float16*)alloc((size_t)B_ * S_ * KIN * 2);    // 67 MB
    _Float16* acts16 = (_Float16*)alloc((size_t)B_ * S_ * NPROC * 2);  // 67 MB
    _Float16* pout16 = (_Float16*)alloc((size_t)NPROC * D_ * 2);       // 8.4 MB
    char* u1 = (char*)alloc((size_t)67108864);
    _Float16* x16 = (_Float16*)u1;
    _Float16* ph  = (_Float16*)(u1 + 16777216);
    _Float16* pl  = (_Float16*)(u1 + 33554432);
    _Float16* WhT = (_Float16*)u1;               // thin path, one batch
    _Float16* WlT = (_Float16*)(u1 + 33554432);
    _Float16* sp  = (_Float16*)u1;
    _Float16* woT = (_Float16*)(u1 + 33554432);

    const size_t WSTRIDE = (size_t)NPROC * KIN;
    size_t off_before_fat = off;
    _Float16* WhA = (_Float16*)alloc((size_t)B_ * WSTRIDE * 2);
    _Float16* WlA = (_Float16*)alloc((size_t)B_ * WSTRIDE * 2);
    bool fat = (off <= ws_size);
    if (!fat) off = off_before_fat;

    hipMemsetAsync(scores, 0, (size_t)B_ * NPROC * 8, stream);

    k_conv_x16 <<<dim3((B_ * S_ * D_ / 4 + 255) / 256), 256, 0, stream>>>(x, x16, B_ * S_ * D_ / 4);
    k_conv_split<<<dim3((NIN * D_ + 255) / 256), 256, 0, stream>>>(patt, ph, pl, NIN * D_);
    k_conv_x16 <<<dim3((NPROC * D_ / 4 + 255) / 256), 256, 0, stream>>>(pout, pout16, NPROC * D_ / 4);

    k_max1<<<dim3(4, 16, 4), 256, 0, stream>>>(x, pmax);
    k_max2<<<dim3(4, 4), 256, 0, stream>>>(pmax, gc64);
    k_router1<<<dim3(128, 4), 256, 0, stream>>>(gc64, W1, b1, hpre);
    k_router2<<<dim3(4), 512, 0, stream>>>(hpre, lng, lnb, W2, b2, qs);
    k_router3<<<dim3(2048, 4), 256, 0, stream>>>(qs, keys, logits);
    k_topk<NIN, KIN><<<dim3(4), 1024, 0, stream>>>(logits, iidx);

    if (fat) {
        // one launch: D (z<4, MFMA-bound, dispatched first) + all-batch gatherW (z>=4, HBM-bound) overlap
        k_fusedDW<<<dim3(16, 32, 36), 256, 0, stream>>>(x16, ph, pl, iidx, a16, pw, WhA, WlA, WSTRIDE);
        k_gemmE<<<dim3(16, 32, 4), 256, 0, stream>>>(a16, WhA, WlA, acts16, scores, 0, WSTRIDE);
    } else {
        k_gemmD<<<dim3(16, 32, 4), 256, 0, stream>>>(x16, ph, pl, iidx, a16);
        for (int b = 0; b < 4; b++) {
            k_gatherW<<<dim3(NPROC, 1), 256, 0, stream>>>(pw, iidx, WhT, WlT, b, 0);
            k_gemmE<<<dim3(16, 32, 1), 256, 0, stream>>>(a16, WhT, WlT, acts16, scores, b, 0);
        }
    }

    k_topk<NPROC, KPROC><<<dim3(4), 1024, 0, stream>>>(scores, pidx);
    k_gatherSP<<<dim3(S_, 4), 256, 0, stream>>>(acts16, pidx, sp);
    k_gatherWoT<<<dim3(KPROC / 64, D_ / 64, 4), 256, 0, stream>>>(pout16, pidx, woT);
    k_gemmF<<<dim3(16, 8, 4), 256, 0, stream>>>(sp, woT, (float*)d_out);
}

// Round 3
// 1546.946 us; speedup vs baseline: 1.0614x; 1.0172x over previous
//
#include <hip/hip_runtime.h>
#include <cstdint>

#define B_    4
#define S_    2048
#define D_    1024
#define NIN   8192
#define NPROC 4096
#define DR    256
#define DR2   512
#define KIN   4096
#define KPROC 2048

typedef _Float16 v8h  __attribute__((ext_vector_type(8)));
typedef _Float16 v4h  __attribute__((ext_vector_type(4)));
typedef float    v4f  __attribute__((ext_vector_type(4)));
typedef float    v16f __attribute__((ext_vector_type(16)));

__device__ __forceinline__ float geluf(float v) {
    return 0.5f * v * (1.0f + erff(v * 0.70710678f));
}

// async global->LDS, 16B per lane. LDS dest semantics: wave-uniform base + lane*16.
__device__ __forceinline__ void cp16(void* lds, const void* g) {
    __builtin_amdgcn_global_load_lds(
        (const __attribute__((address_space(1))) unsigned int*)g,
        (__attribute__((address_space(3))) unsigned int*)lds, 16, 0, 0);
}

// ---------------- converts ----------------
__global__ void k_conv_x16(const float* __restrict__ x, _Float16* __restrict__ x16, int n4) {
    int i = blockIdx.x * 256 + threadIdx.x;
    if (i < n4) {
        float4 v = ((const float4*)x)[i];
        v4h h = { (_Float16)v.x, (_Float16)v.y, (_Float16)v.z, (_Float16)v.w };
        ((v4h*)x16)[i] = h;
    }
}

__global__ void k_conv_split(const float* __restrict__ p, _Float16* __restrict__ ph,
                             _Float16* __restrict__ pl, int n) {
    int i = blockIdx.x * 256 + threadIdx.x;
    if (i < n) {
        float v = p[i];
        _Float16 h = (_Float16)v;
        ph[i] = h;
        pl[i] = (_Float16)(v - (float)h);
    }
}

// ---------------- gc = max over s ----------------
__global__ void k_max1(const float* __restrict__ x, float* __restrict__ pmax) {
    int d = blockIdx.x * 256 + threadIdx.x;
    int chunk = blockIdx.y;
    int b = blockIdx.z;
    const float* base = x + ((size_t)b * S_ + chunk * 128) * D_ + d;
    float m = -3.4e38f;
    for (int s = 0; s < 128; s++) m = fmaxf(m, base[(size_t)s * D_]);
    pmax[((size_t)b * 16 + chunk) * D_ + d] = m;
}

__global__ void k_max2(const float* __restrict__ pmax, double* __restrict__ gc64) {
    int d = blockIdx.x * 256 + threadIdx.x;
    int b = blockIdx.y;
    float m = -3.4e38f;
    for (int c = 0; c < 16; c++) m = fmaxf(m, pmax[((size_t)b * 16 + c) * D_ + d]);
    gc64[(size_t)b * D_ + d] = (double)m;
}

// ---------------- router (fp64) ----------------
__global__ __launch_bounds__(256) void k_router1(
    const double* __restrict__ gc64, const float* __restrict__ W1, const float* __restrict__ b1,
    double* __restrict__ hpre)
{
    int wave = threadIdx.x >> 6, lane = threadIdx.x & 63;
    int j = blockIdx.x * 4 + wave;
    int b = blockIdx.y;
    const double* g = gc64 + (size_t)b * D_;
    const float* w = W1 + (size_t)j * D_;
    double acc = 0.0;
    for (int d = lane; d < D_; d += 64) acc += g[d] * (double)w[d];
#pragma unroll
    for (int o = 32; o > 0; o >>= 1) acc += __shfl_xor(acc, o, 64);
    if (lane == 0) {
        double z = acc + (double)b1[j];
        hpre[(size_t)b * DR2 + j] = 0.5 * z * (1.0 + erf(z * 0.7071067811865475244));
    }
}

__global__ __launch_bounds__(512) void k_router2(
    const double* __restrict__ hpre, const float* __restrict__ lng, const float* __restrict__ lnb,
    const float* __restrict__ W2, const float* __restrict__ b2, double* __restrict__ qs)
{
    __shared__ double sh[DR2];
    __shared__ double red[DR2];
    int b = blockIdx.x, j = threadIdx.x;
    double ge = hpre[(size_t)b * DR2 + j];
    sh[j] = ge; red[j] = ge;
    __syncthreads();
    for (int s = 256; s > 0; s >>= 1) { if (j < s) red[j] += red[j + s]; __syncthreads(); }
    double mu = red[0] / 512.0;
    __syncthreads();
    double dv = ge - mu;
    red[j] = dv * dv;
    __syncthreads();
    for (int s = 256; s > 0; s >>= 1) { if (j < s) red[j] += red[j + s]; __syncthreads(); }
    double rs = 1.0 / sqrt(red[0] / 512.0 + 1e-5);
    __syncthreads();
    sh[j] = dv * rs * (double)lng[j] + (double)lnb[j];
    __syncthreads();
    if (j < DR) {
        double q = (double)b2[j];
        const float* w2r = W2 + (size_t)j * DR2;
        for (int t = 0; t < DR2; t++) q += sh[t] * (double)w2r[t];
        qs[(size_t)b * DR + j] = q;
    }
}

__global__ __launch_bounds__(256) void k_router3(
    const double* __restrict__ qs, const float* __restrict__ keys, double* __restrict__ logits)
{
    int wave = threadIdx.x >> 6, lane = threadIdx.x & 63;
    int n = blockIdx.x * 4 + wave;
    int b = blockIdx.y;
    const double* q = qs + (size_t)b * DR;
    const float* kr = keys + (size_t)n * DR;
    double acc = 0.0;
#pragma unroll
    for (int t = 0; t < 4; t++) {
        int d = lane + t * 64;
        acc += q[d] * (double)kr[d];
    }
#pragma unroll
    for (int o = 32; o > 0; o >>= 1) acc += __shfl_xor(acc, o, 64);
    if (lane == 0) logits[(size_t)b * NIN + n] = acc * 0.0625;
}

// ---------------- top-k ----------------
template<int N, int K>
__global__ __launch_bounds__(1024) void k_topk(const double* __restrict__ vals, int* __restrict__ outIdx) {
    __shared__ unsigned long long keys[N];
    int b = blockIdx.x, tid = threadIdx.x;
    for (int i = tid; i < N; i += 1024) {
        float v = (float)vals[(size_t)b * N + i];
        unsigned int u = __float_as_uint(v);
        u = (u & 0x80000000u) ? ~u : (u | 0x80000000u);
        keys[i] = ((unsigned long long)u << 32) | (unsigned int)(~i);
    }
    __syncthreads();
    for (int k = 2; k <= N; k <<= 1)
        for (int j = k >> 1; j > 0; j >>= 1) {
            for (int i = tid; i < N; i += 1024) {
                int l = i ^ j;
                if (l > i) {
                    unsigned long long a = keys[i], c = keys[l];
                    bool up = ((i & k) == 0);
                    if ((a < c) == up) { keys[i] = c; keys[l] = a; }
                }
            }
            __syncthreads();
        }
    for (int i = tid; i < K; i += 1024)
        outIdx[(size_t)b * K + i] = (int)(~(unsigned int)keys[i]);
}

// ---------------- gather bodies ----------------
__device__ __forceinline__ void dev_gatherW(const float* __restrict__ pw, const int* __restrict__ iidx,
                                            _Float16* __restrict__ Wh, _Float16* __restrict__ Wl,
                                            int p, int b, size_t bstride) {
    const float* row = pw + (size_t)p * NIN;
    const int* ix = iidx + (size_t)b * KIN;
    _Float16* wh = Wh + bstride + (size_t)p * KIN;
    _Float16* wl = Wl + bstride + (size_t)p * KIN;
    for (int j = threadIdx.x; j < KIN; j += 256) {
        float w = row[ix[j]];
        _Float16 h = (_Float16)w;
        wh[j] = h;
        wl[j] = (_Float16)(w - (float)h);
    }
}

__global__ void k_gatherSP(const _Float16* __restrict__ acts16, const int* __restrict__ pidx,
                           _Float16* __restrict__ sp) {
    int s = blockIdx.x, b = blockIdx.y;
    const _Float16* arow = acts16 + ((size_t)b * S_ + s) * NPROC;
    _Float16* orow = sp + ((size_t)b * S_ + s) * KPROC;
    const int* pi = pidx + (size_t)b * KPROC;
    for (int k = threadIdx.x; k < KPROC; k += 256) orow[k] = arow[pi[k]];
}

__global__ void k_gatherWoT(const _Float16* __restrict__ pout16, const int* __restrict__ pidx,
                            _Float16* __restrict__ woT) {
    __shared__ _Float16 t[64][65];
    int k0 = blockIdx.x * 64, d0 = blockIdx.y * 64, b = blockIdx.z;
    const int* pi = pidx + (size_t)b * KPROC;
    for (int i = threadIdx.x; i < 4096; i += 256) {
        int kk = i >> 6, dd = i & 63;
        t[kk][dd] = pout16[(size_t)pi[k0 + kk] * D_ + d0 + dd];
    }
    __syncthreads();
    for (int i = threadIdx.x; i < 4096; i += 256) {
        int dd = i >> 6, kk = i & 63;
        woT[((size_t)b * D_ + d0 + dd) * KPROC + k0 + kk] = t[kk][dd];
    }
}

// XOR-swizzle: LDS physical chunk s of row r holds global chunk s ^ ((r>>1)&3).
// Writer permutes global source per lane; reader XORs its chunk index.

// ---------------- stage D body: sel_acts = gelu(x16 * (ph+pl)^T), 32x32x16 MFMA ----------------
// 128x128 block tile, 2x2 waves, 64x64 wave tile, 3 blocks/CU.
// Counted-vmcnt 2-deep pipeline (T3+T4): loads are NEVER drained to 0 in the main loop.
//   top of iter t: vmcnt(6)  -> buf[t]'s 6 loads landed, t+1's 6 stay in flight
//   barrier; ds_read all frags; lgkmcnt(0); barrier; stage(buf[t] <- t+2); MFMA
// Raw s_barrier (NOT __syncthreads: that drains vmcnt(0)). sched_barrier(0) fences
// stop hipcc hoisting ds_reads above the barrier / MFMAs above the lgkm wait (rule 18).
__device__ __forceinline__ void dev_gemmD(
    const _Float16* __restrict__ x16, const _Float16* __restrict__ ph, const _Float16* __restrict__ pl,
    const int* __restrict__ iidx, _Float16* __restrict__ a16,
    _Float16* tA, _Float16* tBh, _Float16* tBl, int bx, int by, int b)
{
    const int m0 = bx * 128, n0 = by * 128;
    const int tid = threadIdx.x, lane = tid & 63;
    const int wave = tid >> 6, wrow = wave >> 1, wcol = wave & 1;
    const int srow = tid >> 2, spart = tid & 3;
    const int spe = spart ^ ((srow >> 1) & 3);

    const _Float16* as0 = x16 + ((size_t)b * S_ + m0 + srow) * D_ + spe * 8;
    const _Float16* as1 = as0 + (size_t)64 * D_;
    int r0 = iidx[(size_t)b * KIN + n0 + srow];
    int r1 = iidx[(size_t)b * KIN + n0 + srow + 64];
    const _Float16* bh0 = ph + (size_t)r0 * D_ + spe * 8;
    const _Float16* bh1 = ph + (size_t)r1 * D_ + spe * 8;
    const _Float16* bl0 = pl + (size_t)r0 * D_ + spe * 8;
    const _Float16* bl1 = pl + (size_t)r1 * D_ + spe * 8;

    v16f acc[2][2];
#pragma unroll
    for (int i = 0; i < 2; i++)
#pragma unroll
        for (int j = 0; j < 2; j++) acc[i][j] = (v16f)(0.0f);

    const int lrow = lane & 31, lhi = lane >> 5;
    const int swz = (lane >> 1) & 3;
    const int abase = (wrow * 64 + lrow) * 32;
    const int bbase = (wcol * 64 + lrow) * 32;

    const int nt = D_ / 32;
    // prologue: stage step 0 -> buf0, step 1 -> buf1 (12 loads in flight)
    cp16(&tA[tid * 8], as0);
    cp16(&tA[2048 + tid * 8], as1);
    cp16(&tBh[tid * 8], bh0);
    cp16(&tBh[2048 + tid * 8], bh1);
    cp16(&tBl[tid * 8], bl0);
    cp16(&tBl[2048 + tid * 8], bl1);
    cp16(&tA[4096 + tid * 8], as0 + 32);
    cp16(&tA[4096 + 2048 + tid * 8], as1 + 32);
    cp16(&tBh[4096 + tid * 8], bh0 + 32);
    cp16(&tBh[4096 + 2048 + tid * 8], bh1 + 32);
    cp16(&tBl[4096 + tid * 8], bl0 + 32);
    cp16(&tBl[4096 + 2048 + tid * 8], bl1 + 32);

    for (int t = 0; t < nt; t++) {
        const int o = (t & 1) * 4096;
        if (t + 1 < nt) { asm volatile("s_waitcnt vmcnt(6)" ::: "memory"); }
        else            { asm volatile("s_waitcnt vmcnt(0)" ::: "memory"); }
        __builtin_amdgcn_s_barrier();
        __builtin_amdgcn_sched_barrier(0);
        v8h af[2][2], fh[2][2], fl[2][2];
#pragma unroll
        for (int kw = 0; kw < 2; kw++) {
            const int ch = ((kw * 2 + lhi) ^ swz) * 8;
#pragma unroll
            for (int mi = 0; mi < 2; mi++) af[mi][kw] = *(const v8h*)&tA[o + abase + mi * 1024 + ch];
#pragma unroll
            for (int nj = 0; nj < 2; nj++) {
                fh[nj][kw] = *(const v8h*)&tBh[o + bbase + nj * 1024 + ch];
                fl[nj][kw] = *(const v8h*)&tBl[o + bbase + nj * 1024 + ch];
            }
        }
        asm volatile("s_waitcnt lgkmcnt(0)" ::: "memory");
        __builtin_amdgcn_sched_barrier(0);
        __builtin_amdgcn_s_barrier();
        __builtin_amdgcn_sched_barrier(0);
        if (t + 2 < nt) {
            const int kn = (t + 2) * 32;
            cp16(&tA[o + tid * 8], as0 + kn);
            cp16(&tA[o + 2048 + tid * 8], as1 + kn);
            cp16(&tBh[o + tid * 8], bh0 + kn);
            cp16(&tBh[o + 2048 + tid * 8], bh1 + kn);
            cp16(&tBl[o + tid * 8], bl0 + kn);
            cp16(&tBl[o + 2048 + tid * 8], bl1 + kn);
        }
        __builtin_amdgcn_sched_barrier(0);
#pragma unroll
        for (int kw = 0; kw < 2; kw++)
#pragma unroll
            for (int mi = 0; mi < 2; mi++)
#pragma unroll
                for (int nj = 0; nj < 2; nj++) {
                    acc[mi][nj] = __builtin_amdgcn_mfma_f32_32x32x16_f16(af[mi][kw], fh[nj][kw], acc[mi][nj], 0, 0, 0);
                    acc[mi][nj] = __builtin_amdgcn_mfma_f32_32x32x16_f16(af[mi][kw], fl[nj][kw], acc[mi][nj], 0, 0, 0);
                }
    }
#pragma unroll
    for (int mi = 0; mi < 2; mi++)
#pragma unroll
        for (int nj = 0; nj < 2; nj++)
#pragma unroll
            for (int r = 0; r < 16; r++) {
                int row = (r & 3) + 8 * (r >> 2) + 4 * lhi;
                float gv = geluf(acc[mi][nj][r]);
                a16[((size_t)b * S_ + m0 + wrow * 64 + mi * 32 + row) * (size_t)KIN
                    + n0 + wcol * 64 + nj * 32 + lrow] = (_Float16)gv;
            }
}

__global__ __launch_bounds__(256, 3) void k_gemmD(
    const _Float16* __restrict__ x16, const _Float16* __restrict__ ph, const _Float16* __restrict__ pl,
    const int* __restrict__ iidx, _Float16* __restrict__ a16)
{
    __shared__ _Float16 tA[8192], tBh[8192], tBl[8192];
    dev_gemmD(x16, ph, pl, iidx, a16, tA, tBh, tBl, blockIdx.x, blockIdx.y, blockIdx.z);
}

// fused: z<4 -> gemmD batch z; z>=4 -> gatherW block (overlaps MFMA-bound D with HBM-bound gather)
__global__ __launch_bounds__(256, 3) void k_fusedDW(
    const _Float16* __restrict__ x16, const _Float16* __restrict__ ph, const _Float16* __restrict__ pl,
    const int* __restrict__ iidx, _Float16* __restrict__ a16,
    const float* __restrict__ pw, _Float16* __restrict__ Wh, _Float16* __restrict__ Wl, size_t wstride)
{
    __shared__ _Float16 tA[8192], tBh[8192], tBl[8192];
    if (blockIdx.z >= 4) {
        int idx = (blockIdx.z - 4) * 512 + blockIdx.y * 16 + blockIdx.x;  // [0, 16384)
        int p = idx >> 2, b = idx & 3;
        dev_gatherW(pw, iidx, Wh, Wl, p, b, (size_t)b * wstride);
        return;
    }
    dev_gemmD(x16, ph, pl, iidx, a16, tA, tBh, tBl, blockIdx.x, blockIdx.y, blockIdx.z);
}

__global__ void k_gatherW(const float* __restrict__ pw, const int* __restrict__ iidx,
                          _Float16* __restrict__ Wh, _Float16* __restrict__ Wl,
                          int b_base, size_t wstride) {
    dev_gatherW(pw, iidx, Wh, Wl, blockIdx.x, b_base + blockIdx.y, (size_t)blockIdx.y * wstride);
}

// ---------------- stage E: proc_acts = gelu(a16 * (Wh+Wl)^T), 32x32x16, scores += col sums ----------------
__global__ __launch_bounds__(256, 3) void k_gemmE(
    const _Float16* __restrict__ a16, const _Float16* __restrict__ Wh, const _Float16* __restrict__ Wl,
    _Float16* __restrict__ acts16, double* __restrict__ scores, int b_base, size_t wstride)
{
    const int b = b_base + blockIdx.z;
    const int m0 = blockIdx.x * 128, n0 = blockIdx.y * 128;
    __shared__ _Float16 tA[8192], tBh[8192], tBl[8192];
    const int tid = threadIdx.x, lane = tid & 63;
    const int wave = tid >> 6, wrow = wave >> 1, wcol = wave & 1;
    const int srow = tid >> 2, spart = tid & 3;
    const int spe = spart ^ ((srow >> 1) & 3);

    const _Float16* as0 = a16 + ((size_t)b * S_ + m0 + srow) * (size_t)KIN + spe * 8;
    const _Float16* as1 = as0 + (size_t)64 * KIN;
    const _Float16* whB = Wh + (size_t)blockIdx.z * wstride;
    const _Float16* wlB = Wl + (size_t)blockIdx.z * wstride;
    const _Float16* bh0 = whB + (size_t)(n0 + srow) * KIN + spe * 8;
    const _Float16* bh1 = bh0 + (size_t)64 * KIN;
    const _Float16* bl0 = wlB + (size_t)(n0 + srow) * KIN + spe * 8;
    const _Float16* bl1 = bl0 + (size_t)64 * KIN;

    v16f acc[2][2];
#pragma unroll
    for (int i = 0; i < 2; i++)
#pragma unroll
        for (int j = 0; j < 2; j++) acc[i][j] = (v16f)(0.0f);

    const int lrow = lane & 31, lhi = lane >> 5;
    const int swz = (lane >> 1) & 3;
    const int abase = (wrow * 64 + lrow) * 32;
    const int bbase = (wcol * 64 + lrow) * 32;

    const int nt = KIN / 32;
    cp16(&tA[tid * 8], as0);
    cp16(&tA[2048 + tid * 8], as1);
    cp16(&tBh[tid * 8], bh0);
    cp16(&tBh[2048 + tid * 8], bh1);
    cp16(&tBl[tid * 8], bl0);
    cp16(&tBl[2048 + tid * 8], bl1);
    cp16(&tA[4096 + tid * 8], as0 + 32);
    cp16(&tA[4096 + 2048 + tid * 8], as1 + 32);
    cp16(&tBh[4096 + tid * 8], bh0 + 32);
    cp16(&tBh[4096 + 2048 + tid * 8], bh1 + 32);
    cp16(&tBl[4096 + tid * 8], bl0 + 32);
    cp16(&tBl[4096 + 2048 + tid * 8], bl1 + 32);

    for (int t = 0; t < nt; t++) {
        const int o = (t & 1) * 4096;
        if (t + 1 < nt) { asm volatile("s_waitcnt vmcnt(6)" ::: "memory"); }
        else            { asm volatile("s_waitcnt vmcnt(0)" ::: "memory"); }
        __builtin_amdgcn_s_barrier();
        __builtin_amdgcn_sched_barrier(0);
        v8h af[2][2], fh[2][2], fl[2][2];
#pragma unroll
        for (int kw = 0; kw < 2; kw++) {
            const int ch = ((kw * 2 + lhi) ^ swz) * 8;
#pragma unroll
            for (int mi = 0; mi < 2; mi++) af[mi][kw] = *(const v8h*)&tA[o + abase + mi * 1024 + ch];
#pragma unroll
            for (int nj = 0; nj < 2; nj++) {
                fh[nj][kw] = *(const v8h*)&tBh[o + bbase + nj * 1024 + ch];
                fl[nj][kw] = *(const v8h*)&tBl[o + bbase + nj * 1024 + ch];
            }
        }
        asm volatile("s_waitcnt lgkmcnt(0)" ::: "memory");
        __builtin_amdgcn_sched_barrier(0);
        __builtin_amdgcn_s_barrier();
        __builtin_amdgcn_sched_barrier(0);
        if (t + 2 < nt) {
            const int kn = (t + 2) * 32;
            cp16(&tA[o + tid * 8], as0 + kn);
            cp16(&tA[o + 2048 + tid * 8], as1 + kn);
            cp16(&tBh[o + tid * 8], bh0 + kn);
            cp16(&tBh[o + 2048 + tid * 8], bh1 + kn);
            cp16(&tBl[o + tid * 8], bl0 + kn);
            cp16(&tBl[o + 2048 + tid * 8], bl1 + kn);
        }
        __builtin_amdgcn_sched_barrier(0);
#pragma unroll
        for (int kw = 0; kw < 2; kw++)
#pragma unroll
            for (int mi = 0; mi < 2; mi++)
#pragma unroll
                for (int nj = 0; nj < 2; nj++) {
                    acc[mi][nj] = __builtin_amdgcn_mfma_f32_32x32x16_f16(af[mi][kw], fh[nj][kw], acc[mi][nj], 0, 0, 0);
                    acc[mi][nj] = __builtin_amdgcn_mfma_f32_32x32x16_f16(af[mi][kw], fl[nj][kw], acc[mi][nj], 0, 0, 0);
                }
    }
    float psum[2] = {0.f, 0.f};
#pragma unroll
    for (int mi = 0; mi < 2; mi++)
#pragma unroll
        for (int nj = 0; nj < 2; nj++)
#pragma unroll
            for (int r = 0; r < 16; r++) {
                int row = (r & 3) + 8 * (r >> 2) + 4 * lhi;
                float gv = geluf(acc[mi][nj][r]);
                acts16[((size_t)b * S_ + m0 + wrow * 64 + mi * 32 + row) * (size_t)NPROC
                       + n0 + wcol * 64 + nj * 32 + lrow] = (_Float16)gv;
                psum[nj] += gv;
            }
#pragma unroll
    for (int nj = 0; nj < 2; nj++) {
        float s = psum[nj];
        s += __shfl_xor(s, 32, 64);
        if (lhi == 0)
            atomicAdd(&scores[(size_t)b * NPROC + n0 + wcol * 64 + nj * 32 + lrow], (double)s);
    }
}

// ---------------- stage F: out = sp * woT^T (plain f16, 32x32x16) ----------------
__global__ __launch_bounds__(256, 3) void k_gemmF(
    const _Float16* __restrict__ sp, const _Float16* __restrict__ woT, float* __restrict__ out)
{
    const int b = blockIdx.z;
    const int m0 = blockIdx.x * 128, n0 = blockIdx.y * 128;
    __shared__ _Float16 tA[8192], tB[8192];
    const int tid = threadIdx.x, lane = tid & 63;
    const int wave = tid >> 6, wrow = wave >> 1, wcol = wave & 1;
    const int srow = tid >> 2, spart = tid & 3;
    const int spe = spart ^ ((srow >> 1) & 3);

    const _Float16* as0 = sp + ((size_t)b * S_ + m0 + srow) * (size_t)KPROC + spe * 8;
    const _Float16* as1 = as0 + (size_t)64 * KPROC;
    const _Float16* bs0 = woT + ((size_t)b * D_ + n0 + srow) * (size_t)KPROC + spe * 8;
    const _Float16* bs1 = bs0 + (size_t)64 * KPROC;

    v16f acc[2][2];
#pragma unroll
    for (int i = 0; i < 2; i++)
#pragma unroll
        for (int j = 0; j < 2; j++) acc[i][j] = (v16f)(0.0f);

    const int lrow = lane & 31, lhi = lane >> 5;
    const int swz = (lane >> 1) & 3;
    const int abase = (wrow * 64 + lrow) * 32;
    const int bbase = (wcol * 64 + lrow) * 32;

    const int nt = KPROC / 32;
    cp16(&tA[tid * 8], as0);
    cp16(&tA[2048 + tid * 8], as1);
    cp16(&tB[tid * 8], bs0);
    cp16(&tB[2048 + tid * 8], bs1);
    cp16(&tA[4096 + tid * 8], as0 + 32);
    cp16(&tA[4096 + 2048 + tid * 8], as1 + 32);
    cp16(&tB[4096 + tid * 8], bs0 + 32);
    cp16(&tB[4096 + 2048 + tid * 8], bs1 + 32);

    for (int t = 0; t < nt; t++) {
        const int o = (t & 1) * 4096;
        if (t + 1 < nt) { asm volatile("s_waitcnt vmcnt(4)" ::: "memory"); }
        else            { asm volatile("s_waitcnt vmcnt(0)" ::: "memory"); }
        __builtin_amdgcn_s_barrier();
        __builtin_amdgcn_sched_barrier(0);
        v8h af[2][2], bf[2][2];
#pragma unroll
        for (int kw = 0; kw < 2; kw++) {
            const int ch = ((kw * 2 + lhi) ^ swz) * 8;
#pragma unroll
            for (int mi = 0; mi < 2; mi++) af[mi][kw] = *(const v8h*)&tA[o + abase + mi * 1024 + ch];
#pragma unroll
            for (int nj = 0; nj < 2; nj++) bf[nj][kw] = *(const v8h*)&tB[o + bbase + nj * 1024 + ch];
        }
        asm volatile("s_waitcnt lgkmcnt(0)" ::: "memory");
        __builtin_amdgcn_sched_barrier(0);
        __builtin_amdgcn_s_barrier();
        __builtin_amdgcn_sched_barrier(0);
        if (t + 2 < nt) {
            const int kn = (t + 2) * 32;
            cp16(&tA[o + tid * 8], as0 + kn);
            cp16(&tA[o + 2048 + tid * 8], as1 + kn);
            cp16(&tB[o + tid * 8], bs0 + kn);
            cp16(&tB[o + 2048 + tid * 8], bs1 + kn);
        }
        __builtin_amdgcn_sched_barrier(0);
#pragma unroll
        for (int kw = 0; kw < 2; kw++)
#pragma unroll
            for (int mi = 0; mi < 2; mi++)
#pragma unroll
                for (int nj = 0; nj < 2; nj++)
                    acc[mi][nj] = __builtin_amdgcn_mfma_f32_32x32x16_f16(af[mi][kw], bf[nj][kw], acc[mi][nj], 0, 0, 0);
    }
#pragma unroll
    for (int mi = 0; mi < 2; mi++)
#pragma unroll
        for (int nj = 0; nj < 2; nj++)
#pragma unroll
            for (int r = 0; r < 16; r++) {
                int row = (r & 3) + 8 * (r >> 2) + 4 * lhi;
                out[((size_t)b * S_ + m0 + wrow * 64 + mi * 32 + row) * (size_t)D_
                    + n0 + wcol * 64 + nj * 32 + lrow] = acc[mi][nj][r];
            }
}

// ---------------- host ----------------
extern "C" void kernel_launch(void* const* d_in, const int* in_sizes, int n_in,
                              void* d_out, int out_size, void* d_ws, size_t ws_size,
                              hipStream_t stream) {
    const float* x    = (const float*)d_in[0];
    const float* W1   = (const float*)d_in[1];
    const float* b1   = (const float*)d_in[2];
    const float* lng  = (const float*)d_in[3];
    const float* lnb  = (const float*)d_in[4];
    const float* W2   = (const float*)d_in[5];
    const float* b2   = (const float*)d_in[6];
    const float* keys = (const float*)d_in[7];
    const float* patt = (const float*)d_in[8];
    const float* pw   = (const float*)d_in[9];
    const float* pout = (const float*)d_in[10];
    (void)in_sizes; (void)n_in; (void)out_size;

    char* w = (char*)d_ws;
    size_t off = 0;
    auto alloc = [&](size_t bytes) -> void* {
        void* p = w + off;
        off += (bytes + 255) & ~(size_t)255;
        return p;
    };
    double* gc64   = (double*)alloc((size_t)B_ * D_ * 8);
    float*  pmax   = (float*) alloc((size_t)B_ * 16 * D_ * 4);
    double* logits = (double*)alloc((size_t)B_ * NIN * 8);
    double* scores = (double*)alloc((size_t)B_ * NPROC * 8);
    double* hpre   = (double*)alloc((size_t)B_ * DR2 * 8);
    double* qs     = (double*)alloc((size_t)B_ * DR * 8);
    int*    iidx   = (int*)   alloc((size_t)B_ * KIN * 4);
    int*    pidx   = (int*)   alloc((size_t)B_ * KPROC * 4);
    _Float16* a16    = (_Float16*)alloc((size_t)B_ * S_ * KIN * 2);    // 67 MB
    _Float16* acts16 = (_Float16*)alloc((size_t)B_ * S_ * NPROC * 2);  // 67 MB
    _Float16* pout16 = (_Float16*)alloc((size_t)NPROC * D_ * 2);       // 8.4 MB
    char* u1 = (char*)alloc((size_t)67108864);
    _Float16* x16 = (_Float16*)u1;
    _Float16* ph  = (_Float16*)(u1 + 16777216);
    _Float16* pl  = (_Float16*)(u1 + 33554432);
    _Float16* WhT = (_Float16*)u1;               // thin path, one batch
    _Float16* WlT = (_Float16*)(u1 + 33554432);
    _Float16* sp  = (_Float16*)u1;
    _Float16* woT = (_Float16*)(u1 + 33554432);

    const size_t WSTRIDE = (size_t)NPROC * KIN;
    size_t off_before_fat = off;
    _Float16* WhA = (_Float16*)alloc((size_t)B_ * WSTRIDE * 2);
    _Float16* WlA = (_Float16*)alloc((size_t)B_ * WSTRIDE * 2);
    bool fat = (off <= ws_size);
    if (!fat) off = off_before_fat;

    hipMemsetAsync(scores, 0, (size_t)B_ * NPROC * 8, stream);

    k_conv_x16 <<<dim3((B_ * S_ * D_ / 4 + 255) / 256), 256, 0, stream>>>(x, x16, B_ * S_ * D_ / 4);
    k_conv_split<<<dim3((NIN * D_ + 255) / 256), 256, 0, stream>>>(patt, ph, pl, NIN * D_);
    k_conv_x16 <<<dim3((NPROC * D_ / 4 + 255) / 256), 256, 0, stream>>>(pout, pout16, NPROC * D_ / 4);

    k_max1<<<dim3(4, 16, 4), 256, 0, stream>>>(x, pmax);
    k_max2<<<dim3(4, 4), 256, 0, stream>>>(pmax, gc64);
    k_router1<<<dim3(128, 4), 256, 0, stream>>>(gc64, W1, b1, hpre);
    k_router2<<<dim3(4), 512, 0, stream>>>(hpre, lng, lnb, W2, b2, qs);
    k_router3<<<dim3(2048, 4), 256, 0, stream>>>(qs, keys, logits);
    k_topk<NIN, KIN><<<dim3(4), 1024, 0, stream>>>(logits, iidx);

    if (fat) {
        // one launch: D (z<4, MFMA-bound, dispatched first) + all-batch gatherW (z>=4, HBM-bound) overlap
        k_fusedDW<<<dim3(16, 32, 36), 256, 0, stream>>>(x16, ph, pl, iidx, a16, pw, WhA, WlA, WSTRIDE);
        k_gemmE<<<dim3(16, 32, 4), 256, 0, stream>>>(a16, WhA, WlA, acts16, scores, 0, WSTRIDE);
    } else {
        k_gemmD<<<dim3(16, 32, 4), 256, 0, stream>>>(x16, ph, pl, iidx, a16);
        for (int b = 0; b < 4; b++) {
            k_gatherW<<<dim3(NPROC, 1), 256, 0, stream>>>(pw, iidx, WhT, WlT, b, 0);
            k_gemmE<<<dim3(16, 32, 1), 256, 0, stream>>>(a16, WhT, WlT, acts16, scores, b, 0);
        }
    }

    k_topk<NPROC, KPROC><<<dim3(4), 1024, 0, stream>>>(scores, pidx);
    k_gatherSP<<<dim3(S_, 4), 256, 0, stream>>>(acts16, pidx, sp);
    k_gatherWoT<<<dim3(KPROC / 64, D_ / 64, 4), 256, 0, stream>>>(pout16, pidx, woT);
    k_gemmF<<<dim3(16, 8, 4), 256, 0, stream>>>(sp, woT, (float*)d_out);
}

// Round 5
// 1494.970 us; speedup vs baseline: 1.0983x; 1.0348x over previous
//
#include <hip/hip_runtime.h>
#include <cstdint>

#define B_    4
#define S_    2048
#define D_    1024
#define NIN   8192
#define NPROC 4096
#define DR    256
#define DR2   512
#define KIN   4096
#define KPROC 2048

typedef _Float16 v8h  __attribute__((ext_vector_type(8)));
typedef _Float16 v4h  __attribute__((ext_vector_type(4)));
typedef float    v4f  __attribute__((ext_vector_type(4)));
typedef float    v16f __attribute__((ext_vector_type(16)));

__device__ __forceinline__ float geluf(float v) {
    return 0.5f * v * (1.0f + erff(v * 0.70710678f));
}

// async global->LDS, 16B per lane. LDS dest semantics: wave-uniform base + lane*16.
__device__ __forceinline__ void cp16(void* lds, const void* g) {
    __builtin_amdgcn_global_load_lds(
        (const __attribute__((address_space(1))) unsigned int*)g,
        (__attribute__((address_space(3))) unsigned int*)lds, 16, 0, 0);
}

// ---------------- converts ----------------
__global__ void k_conv_x16(const float* __restrict__ x, _Float16* __restrict__ x16, int n4) {
    int i = blockIdx.x * 256 + threadIdx.x;
    if (i < n4) {
        float4 v = ((const float4*)x)[i];
        v4h h = { (_Float16)v.x, (_Float16)v.y, (_Float16)v.z, (_Float16)v.w };
        ((v4h*)x16)[i] = h;
    }
}

__global__ void k_conv_split(const float* __restrict__ p, _Float16* __restrict__ ph,
                             _Float16* __restrict__ pl, int n) {
    int i = blockIdx.x * 256 + threadIdx.x;
    if (i < n) {
        float v = p[i];
        _Float16 h = (_Float16)v;
        ph[i] = h;
        pl[i] = (_Float16)(v - (float)h);
    }
}

// ---------------- gc = max over s ----------------
__global__ void k_max1(const float* __restrict__ x, float* __restrict__ pmax) {
    int d = blockIdx.x * 256 + threadIdx.x;
    int chunk = blockIdx.y;
    int b = blockIdx.z;
    const float* base = x + ((size_t)b * S_ + chunk * 128) * D_ + d;
    float m = -3.4e38f;
    for (int s = 0; s < 128; s++) m = fmaxf(m, base[(size_t)s * D_]);
    pmax[((size_t)b * 16 + chunk) * D_ + d] = m;
}

__global__ void k_max2(const float* __restrict__ pmax, double* __restrict__ gc64) {
    int d = blockIdx.x * 256 + threadIdx.x;
    int b = blockIdx.y;
    float m = -3.4e38f;
    for (int c = 0; c < 16; c++) m = fmaxf(m, pmax[((size_t)b * 16 + c) * D_ + d]);
    gc64[(size_t)b * D_ + d] = (double)m;
}

// ---------------- router (fp64) ----------------
__global__ __launch_bounds__(256) void k_router1(
    const double* __restrict__ gc64, const float* __restrict__ W1, const float* __restrict__ b1,
    double* __restrict__ hpre)
{
    int wave = threadIdx.x >> 6, lane = threadIdx.x & 63;
    int j = blockIdx.x * 4 + wave;
    int b = blockIdx.y;
    const double* g = gc64 + (size_t)b * D_;
    const float* w = W1 + (size_t)j * D_;
    double acc = 0.0;
    for (int d = lane; d < D_; d += 64) acc += g[d] * (double)w[d];
#pragma unroll
    for (int o = 32; o > 0; o >>= 1) acc += __shfl_xor(acc, o, 64);
    if (lane == 0) {
        double z = acc + (double)b1[j];
        hpre[(size_t)b * DR2 + j] = 0.5 * z * (1.0 + erf(z * 0.7071067811865475244));
    }
}

__global__ __launch_bounds__(512) void k_router2(
    const double* __restrict__ hpre, const float* __restrict__ lng, const float* __restrict__ lnb,
    const float* __restrict__ W2, const float* __restrict__ b2, double* __restrict__ qs)
{
    __shared__ double sh[DR2];
    __shared__ double red[DR2];
    int b = blockIdx.x, j = threadIdx.x;
    double ge = hpre[(size_t)b * DR2 + j];
    sh[j] = ge; red[j] = ge;
    __syncthreads();
    for (int s = 256; s > 0; s >>= 1) { if (j < s) red[j] += red[j + s]; __syncthreads(); }
    double mu = red[0] / 512.0;
    __syncthreads();
    double dv = ge - mu;
    red[j] = dv * dv;
    __syncthreads();
    for (int s = 256; s > 0; s >>= 1) { if (j < s) red[j] += red[j + s]; __syncthreads(); }
    double rs = 1.0 / sqrt(red[0] / 512.0 + 1e-5);
    __syncthreads();
    sh[j] = dv * rs * (double)lng[j] + (double)lnb[j];
    __syncthreads();
    if (j < DR) {
        double q = (double)b2[j];
        const float* w2r = W2 + (size_t)j * DR2;
        for (int t = 0; t < DR2; t++) q += sh[t] * (double)w2r[t];
        qs[(size_t)b * DR + j] = q;
    }
}

__global__ __launch_bounds__(256) void k_router3(
    const double* __restrict__ qs, const float* __restrict__ keys, double* __restrict__ logits)
{
    int wave = threadIdx.x >> 6, lane = threadIdx.x & 63;
    int n = blockIdx.x * 4 + wave;
    int b = blockIdx.y;
    const double* q = qs + (size_t)b * DR;
    const float* kr = keys + (size_t)n * DR;
    double acc = 0.0;
#pragma unroll
    for (int t = 0; t < 4; t++) {
        int d = lane + t * 64;
        acc += q[d] * (double)kr[d];
    }
#pragma unroll
    for (int o = 32; o > 0; o >>= 1) acc += __shfl_xor(acc, o, 64);
    if (lane == 0) logits[(size_t)b * NIN + n] = acc * 0.0625;
}

// ---------------- top-k ----------------
template<int N, int K>
__global__ __launch_bounds__(1024) void k_topk(const double* __restrict__ vals, int* __restrict__ outIdx) {
    __shared__ unsigned long long keys[N];
    int b = blockIdx.x, tid = threadIdx.x;
    for (int i = tid; i < N; i += 1024) {
        float v = (float)vals[(size_t)b * N + i];
        unsigned int u = __float_as_uint(v);
        u = (u & 0x80000000u) ? ~u : (u | 0x80000000u);
        keys[i] = ((unsigned long long)u << 32) | (unsigned int)(~i);
    }
    __syncthreads();
    for (int k = 2; k <= N; k <<= 1)
        for (int j = k >> 1; j > 0; j >>= 1) {
            for (int i = tid; i < N; i += 1024) {
                int l = i ^ j;
                if (l > i) {
                    unsigned long long a = keys[i], c = keys[l];
                    bool up = ((i & k) == 0);
                    if ((a < c) == up) { keys[i] = c; keys[l] = a; }
                }
            }
            __syncthreads();
        }
    for (int i = tid; i < K; i += 1024)
        outIdx[(size_t)b * K + i] = (int)(~(unsigned int)keys[i]);
}

// ---------------- gather bodies ----------------
__device__ __forceinline__ void dev_gatherW(const float* __restrict__ pw, const int* __restrict__ iidx,
                                            _Float16* __restrict__ Wh, _Float16* __restrict__ Wl,
                                            int p, int b, size_t bstride) {
    const float* row = pw + (size_t)p * NIN;
    const int* ix = iidx + (size_t)b * KIN;
    _Float16* wh = Wh + bstride + (size_t)p * KIN;
    _Float16* wl = Wl + bstride + (size_t)p * KIN;
    for (int j = threadIdx.x; j < KIN; j += 256) {
        float w = row[ix[j]];
        _Float16 h = (_Float16)w;
        wh[j] = h;
        wl[j] = (_Float16)(w - (float)h);
    }
}

__global__ void k_gatherSP(const _Float16* __restrict__ acts16, const int* __restrict__ pidx,
                           _Float16* __restrict__ sp) {
    int s = blockIdx.x, b = blockIdx.y;
    const _Float16* arow = acts16 + ((size_t)b * S_ + s) * NPROC;
    _Float16* orow = sp + ((size_t)b * S_ + s) * KPROC;
    const int* pi = pidx + (size_t)b * KPROC;
    for (int k = threadIdx.x; k < KPROC; k += 256) orow[k] = arow[pi[k]];
}

__global__ void k_gatherWoT(const _Float16* __restrict__ pout16, const int* __restrict__ pidx,
                            _Float16* __restrict__ woT) {
    __shared__ _Float16 t[64][65];
    int k0 = blockIdx.x * 64, d0 = blockIdx.y * 64, b = blockIdx.z;
    const int* pi = pidx + (size_t)b * KPROC;
    for (int i = threadIdx.x; i < 4096; i += 256) {
        int kk = i >> 6, dd = i & 63;
        t[kk][dd] = pout16[(size_t)pi[k0 + kk] * D_ + d0 + dd];
    }
    __syncthreads();
    for (int i = threadIdx.x; i < 4096; i += 256) {
        int dd = i >> 6, kk = i & 63;
        woT[((size_t)b * D_ + d0 + dd) * KPROC + k0 + kk] = t[kk][dd];
    }
}

// XOR-swizzle: LDS physical chunk s of row r holds global chunk s ^ ((r>>1)&3).
// Writer permutes global source per lane; reader XORs its chunk index.
// Pattern period is 8 rows; all stage chunks are 64-row groups (64 % 8 == 0).

// ---------------- stage D body: sel_acts = gelu(x16 * (ph+pl)^T), 32x32x16 MFMA ----------------
// 256x128 block tile, 2x2 waves, wave tile 128x64 (mi=4, nj=2): 0.5 LDS-reads/MFMA.
// Counted-vmcnt 2-deep pipeline (T3+T4): 16 loads in flight, vmcnt(8) at iter top.
// LDS layout per buffer: A = 256 rows x 32 cols = 8192 halfs (row r at r*32);
// B = 128 rows x 32 = 4096 halfs. Buffer strides: oA = buf*8192, oB = buf*4096.
// Fragment reads: row = wrow*128 + mi*32 + lrow  ->  tA[oA + (wrow*128+lrow)*32 + mi*1024 + ch].
__device__ __forceinline__ void dev_gemmD(
    const _Float16* __restrict__ x16, const _Float16* __restrict__ ph, const _Float16* __restrict__ pl,
    const int* __restrict__ iidx, _Float16* __restrict__ a16,
    _Float16* tA, _Float16* tBh, _Float16* tBl, int bx, int by, int b)
{
    const int m0 = bx * 256, n0 = by * 128;
    const int tid = threadIdx.x, lane = tid & 63;
    const int wave = tid >> 6, wrow = wave >> 1, wcol = wave & 1;
    const int srow = tid >> 2, spart = tid & 3;
    const int spe = spart ^ ((srow >> 1) & 3);

    const _Float16* as0 = x16 + ((size_t)b * S_ + m0 + srow) * D_ + spe * 8;
    int r0 = iidx[(size_t)b * KIN + n0 + srow];
    int r1 = iidx[(size_t)b * KIN + n0 + srow + 64];
    const _Float16* bh0 = ph + (size_t)r0 * D_ + spe * 8;
    const _Float16* bh1 = ph + (size_t)r1 * D_ + spe * 8;
    const _Float16* bl0 = pl + (size_t)r0 * D_ + spe * 8;
    const _Float16* bl1 = pl + (size_t)r1 * D_ + spe * 8;

    v16f acc[4][2];
#pragma unroll
    for (int i = 0; i < 4; i++)
#pragma unroll
        for (int j = 0; j < 2; j++) acc[i][j] = (v16f)(0.0f);

    const int lrow = lane & 31, lhi = lane >> 5;
    const int swz = (lane >> 1) & 3;
    const int abase = (wrow * 128 + lrow) * 32;
    const int bbase = (wcol * 64 + lrow) * 32;

    auto STAGE = [&](int buf, int kt) {
        const int oA = buf * 8192, oB = buf * 4096;
        cp16(&tA[oA + tid * 8],        as0 + kt);
        cp16(&tA[oA + 2048 + tid * 8], as0 + (size_t)64 * D_ + kt);
        cp16(&tA[oA + 4096 + tid * 8], as0 + (size_t)128 * D_ + kt);
        cp16(&tA[oA + 6144 + tid * 8], as0 + (size_t)192 * D_ + kt);
        cp16(&tBh[oB + tid * 8],        bh0 + kt);
        cp16(&tBh[oB + 2048 + tid * 8], bh1 + kt);
        cp16(&tBl[oB + tid * 8],        bl0 + kt);
        cp16(&tBl[oB + 2048 + tid * 8], bl1 + kt);
    };

    const int nt = D_ / 32;
    STAGE(0, 0);
    STAGE(1, 32);

    for (int t = 0; t < nt; t++) {
        const int oA = (t & 1) * 8192, oB = (t & 1) * 4096;
        if (t + 1 < nt) { asm volatile("s_waitcnt vmcnt(8)" ::: "memory"); }
        else            { asm volatile("s_waitcnt vmcnt(0)" ::: "memory"); }
        __builtin_amdgcn_s_barrier();
        __builtin_amdgcn_sched_barrier(0);
        v8h af[4][2], fh[2][2], fl[2][2];
#pragma unroll
        for (int kw = 0; kw < 2; kw++) {
            const int ch = ((kw * 2 + lhi) ^ swz) * 8;
#pragma unroll
            for (int mi = 0; mi < 4; mi++) af[mi][kw] = *(const v8h*)&tA[oA + abase + mi * 1024 + ch];
#pragma unroll
            for (int nj = 0; nj < 2; nj++) {
                fh[nj][kw] = *(const v8h*)&tBh[oB + bbase + nj * 1024 + ch];
                fl[nj][kw] = *(const v8h*)&tBl[oB + bbase + nj * 1024 + ch];
            }
        }
        asm volatile("s_waitcnt lgkmcnt(0)" ::: "memory");
        __builtin_amdgcn_sched_barrier(0);
        __builtin_amdgcn_s_barrier();
        __builtin_amdgcn_sched_barrier(0);
        if (t + 2 < nt) STAGE(t & 1, (t + 2) * 32);
        __builtin_amdgcn_sched_barrier(0);
        __builtin_amdgcn_s_setprio(1);
#pragma unroll
        for (int kw = 0; kw < 2; kw++)
#pragma unroll
            for (int mi = 0; mi < 4; mi++)
#pragma unroll
                for (int nj = 0; nj < 2; nj++) {
                    acc[mi][nj] = __builtin_amdgcn_mfma_f32_32x32x16_f16(af[mi][kw], fh[nj][kw], acc[mi][nj], 0, 0, 0);
                    acc[mi][nj] = __builtin_amdgcn_mfma_f32_32x32x16_f16(af[mi][kw], fl[nj][kw], acc[mi][nj], 0, 0, 0);
                }
        __builtin_amdgcn_s_setprio(0);
    }
#pragma unroll
    for (int mi = 0; mi < 4; mi++)
#pragma unroll
        for (int nj = 0; nj < 2; nj++)
#pragma unroll
            for (int r = 0; r < 16; r++) {
                int row = (r & 3) + 8 * (r >> 2) + 4 * lhi;
                float gv = geluf(acc[mi][nj][r]);
                a16[((size_t)b * S_ + m0 + wrow * 128 + mi * 32 + row) * (size_t)KIN
                    + n0 + wcol * 64 + nj * 32 + lrow] = (_Float16)gv;
            }
}

__global__ __launch_bounds__(256, 2) void k_gemmD(
    const _Float16* __restrict__ x16, const _Float16* __restrict__ ph, const _Float16* __restrict__ pl,
    const int* __restrict__ iidx, _Float16* __restrict__ a16)
{
    __shared__ _Float16 tA[16384], tBh[8192], tBl[8192];
    dev_gemmD(x16, ph, pl, iidx, a16, tA, tBh, tBl, blockIdx.x, blockIdx.y, blockIdx.z);
}

// fused: z<4 -> gemmD batch z; z>=4 -> gatherW block (overlaps MFMA-bound D with HBM-bound gather)
__global__ __launch_bounds__(256, 2) void k_fusedDW(
    const _Float16* __restrict__ x16, const _Float16* __restrict__ ph, const _Float16* __restrict__ pl,
    const int* __restrict__ iidx, _Float16* __restrict__ a16,
    const float* __restrict__ pw, _Float16* __restrict__ Wh, _Float16* __restrict__ Wl, size_t wstride)
{
    __shared__ _Float16 tA[16384], tBh[8192], tBl[8192];
    if (blockIdx.z >= 4) {
        int idx = (blockIdx.z - 4) * 256 + blockIdx.y * 8 + blockIdx.x;  // [0, 16384)
        int p = idx >> 2, b = idx & 3;
        dev_gatherW(pw, iidx, Wh, Wl, p, b, (size_t)b * wstride);
        return;
    }
    dev_gemmD(x16, ph, pl, iidx, a16, tA, tBh, tBl, blockIdx.x, blockIdx.y, blockIdx.z);
}

__global__ void k_gatherW(const float* __restrict__ pw, const int* __restrict__ iidx,
                          _Float16* __restrict__ Wh, _Float16* __restrict__ Wl,
                          int b_base, size_t wstride) {
    dev_gatherW(pw, iidx, Wh, Wl, blockIdx.x, b_base + blockIdx.y, (size_t)blockIdx.y * wstride);
}

// ---------------- stage E: proc_acts = gelu(a16 * (Wh+Wl)^T), 32x32x16, scores += col sums ----------------
__global__ __launch_bounds__(256, 2) void k_gemmE(
    const _Float16* __restrict__ a16, const _Float16* __restrict__ Wh, const _Float16* __restrict__ Wl,
    _Float16* __restrict__ acts16, double* __restrict__ scores, int b_base, size_t wstride)
{
    const int b = b_base + blockIdx.z;
    const int m0 = blockIdx.x * 256, n0 = blockIdx.y * 128;
    __shared__ _Float16 tA[16384], tBh[8192], tBl[8192];
    const int tid = threadIdx.x, lane = tid & 63;
    const int wave = tid >> 6, wrow = wave >> 1, wcol = wave & 1;
    const int srow = tid >> 2, spart = tid & 3;
    const int spe = spart ^ ((srow >> 1) & 3);

    const _Float16* as0 = a16 + ((size_t)b * S_ + m0 + srow) * (size_t)KIN + spe * 8;
    const _Float16* whB = Wh + (size_t)blockIdx.z * wstride;
    const _Float16* wlB = Wl + (size_t)blockIdx.z * wstride;
    const _Float16* bh0 = whB + (size_t)(n0 + srow) * KIN + spe * 8;
    const _Float16* bh1 = bh0 + (size_t)64 * KIN;
    const _Float16* bl0 = wlB + (size_t)(n0 + srow) * KIN + spe * 8;
    const _Float16* bl1 = bl0 + (size_t)64 * KIN;

    v16f acc[4][2];
#pragma unroll
    for (int i = 0; i < 4; i++)
#pragma unroll
        for (int j = 0; j < 2; j++) acc[i][j] = (v16f)(0.0f);

    const int lrow = lane & 31, lhi = lane >> 5;
    const int swz = (lane >> 1) & 3;
    const int abase = (wrow * 128 + lrow) * 32;
    const int bbase = (wcol * 64 + lrow) * 32;

    auto STAGE = [&](int buf, int kt) {
        const int oA = buf * 8192, oB = buf * 4096;
        cp16(&tA[oA + tid * 8],        as0 + kt);
        cp16(&tA[oA + 2048 + tid * 8], as0 + (size_t)64 * KIN + kt);
        cp16(&tA[oA + 4096 + tid * 8], as0 + (size_t)128 * KIN + kt);
        cp16(&tA[oA + 6144 + tid * 8], as0 + (size_t)192 * KIN + kt);
        cp16(&tBh[oB + tid * 8],        bh0 + kt);
        cp16(&tBh[oB + 2048 + tid * 8], bh1 + kt);
        cp16(&tBl[oB + tid * 8],        bl0 + kt);
        cp16(&tBl[oB + 2048 + tid * 8], bl1 + kt);
    };

    const int nt = KIN / 32;
    STAGE(0, 0);
    STAGE(1, 32);

    for (int t = 0; t < nt; t++) {
        const int oA = (t & 1) * 8192, oB = (t & 1) * 4096;
        if (t + 1 < nt) { asm volatile("s_waitcnt vmcnt(8)" ::: "memory"); }
        else            { asm volatile("s_waitcnt vmcnt(0)" ::: "memory"); }
        __builtin_amdgcn_s_barrier();
        __builtin_amdgcn_sched_barrier(0);
        v8h af[4][2], fh[2][2], fl[2][2];
#pragma unroll
        for (int kw = 0; kw < 2; kw++) {
            const int ch = ((kw * 2 + lhi) ^ swz) * 8;
#pragma unroll
            for (int mi = 0; mi < 4; mi++) af[mi][kw] = *(const v8h*)&tA[oA + abase + mi * 1024 + ch];
#pragma unroll
            for (int nj = 0; nj < 2; nj++) {
                fh[nj][kw] = *(const v8h*)&tBh[oB + bbase + nj * 1024 + ch];
                fl[nj][kw] = *(const v8h*)&tBl[oB + bbase + nj * 1024 + ch];
            }
        }
        asm volatile("s_waitcnt lgkmcnt(0)" ::: "memory");
        __builtin_amdgcn_sched_barrier(0);
        __builtin_amdgcn_s_barrier();
        __builtin_amdgcn_sched_barrier(0);
        if (t + 2 < nt) STAGE(t & 1, (t + 2) * 32);
        __builtin_amdgcn_sched_barrier(0);
        __builtin_amdgcn_s_setprio(1);
#pragma unroll
        for (int kw = 0; kw < 2; kw++)
#pragma unroll
            for (int mi = 0; mi < 4; mi++)
#pragma unroll
                for (int nj = 0; nj < 2; nj++) {
                    acc[mi][nj] = __builtin_amdgcn_mfma_f32_32x32x16_f16(af[mi][kw], fh[nj][kw], acc[mi][nj], 0, 0, 0);
                    acc[mi][nj] = __builtin_amdgcn_mfma_f32_32x32x16_f16(af[mi][kw], fl[nj][kw], acc[mi][nj], 0, 0, 0);
                }
        __builtin_amdgcn_s_setprio(0);
    }
    float psum[2] = {0.f, 0.f};
#pragma unroll
    for (int mi = 0; mi < 4; mi++)
#pragma unroll
        for (int nj = 0; nj < 2; nj++)
#pragma unroll
            for (int r = 0; r < 16; r++) {
                int row = (r & 3) + 8 * (r >> 2) + 4 * lhi;
                float gv = geluf(acc[mi][nj][r]);
                acts16[((size_t)b * S_ + m0 + wrow * 128 + mi * 32 + row) * (size_t)NPROC
                       + n0 + wcol * 64 + nj * 32 + lrow] = (_Float16)gv;
                psum[nj] += gv;
            }
#pragma unroll
    for (int nj = 0; nj < 2; nj++) {
        float s = psum[nj];
        s += __shfl_xor(s, 32, 64);
        if (lhi == 0)
            atomicAdd(&scores[(size_t)b * NPROC + n0 + wcol * 64 + nj * 32 + lrow], (double)s);
    }
}

// ---------------- stage F: out = sp * woT^T (plain f16, 32x32x16) ----------------
__global__ __launch_bounds__(256, 2) void k_gemmF(
    const _Float16* __restrict__ sp, const _Float16* __restrict__ woT, float* __restrict__ out)
{
    const int b = blockIdx.z;
    const int m0 = blockIdx.x * 256, n0 = blockIdx.y * 128;
    __shared__ _Float16 tA[16384], tB[8192];
    const int tid = threadIdx.x, lane = tid & 63;
    const int wave = tid >> 6, wrow = wave >> 1, wcol = wave & 1;
    const int srow = tid >> 2, spart = tid & 3;
    const int spe = spart ^ ((srow >> 1) & 3);

    const _Float16* as0 = sp + ((size_t)b * S_ + m0 + srow) * (size_t)KPROC + spe * 8;
    const _Float16* bs0 = woT + ((size_t)b * D_ + n0 + srow) * (size_t)KPROC + spe * 8;
    const _Float16* bs1 = bs0 + (size_t)64 * KPROC;

    v16f acc[4][2];
#pragma unroll
    for (int i = 0; i < 4; i++)
#pragma unroll
        for (int j = 0; j < 2; j++) acc[i][j] = (v16f)(0.0f);

    const int lrow = lane & 31, lhi = lane >> 5;
    const int swz = (lane >> 1) & 3;
    const int abase = (wrow * 128 + lrow) * 32;
    const int bbase = (wcol * 64 + lrow) * 32;

    auto STAGE = [&](int buf, int kt) {
        const int oA = buf * 8192, oB = buf * 4096;
        cp16(&tA[oA + tid * 8],        as0 + kt);
        cp16(&tA[oA + 2048 + tid * 8], as0 + (size_t)64 * KPROC + kt);
        cp16(&tA[oA + 4096 + tid * 8], as0 + (size_t)128 * KPROC + kt);
        cp16(&tA[oA + 6144 + tid * 8], as0 + (size_t)192 * KPROC + kt);
        cp16(&tB[oB + tid * 8],        bs0 + kt);
        cp16(&tB[oB + 2048 + tid * 8], bs1 + kt);
    };

    const int nt = KPROC / 32;
    STAGE(0, 0);
    STAGE(1, 32);

    for (int t = 0; t < nt; t++) {
        const int oA = (t & 1) * 8192, oB = (t & 1) * 4096;
        if (t + 1 < nt) { asm volatile("s_waitcnt vmcnt(6)" ::: "memory"); }
        else            { asm volatile("s_waitcnt vmcnt(0)" ::: "memory"); }
        __builtin_amdgcn_s_barrier();
        __builtin_amdgcn_sched_barrier(0);
        v8h af[4][2], bf[2][2];
#pragma unroll
        for (int kw = 0; kw < 2; kw++) {
            const int ch = ((kw * 2 + lhi) ^ swz) * 8;
#pragma unroll
            for (int mi = 0; mi < 4; mi++) af[mi][kw] = *(const v8h*)&tA[oA + abase + mi * 1024 + ch];
#pragma unroll
            for (int nj = 0; nj < 2; nj++) bf[nj][kw] = *(const v8h*)&tB[oB + bbase + nj * 1024 + ch];
        }
        asm volatile("s_waitcnt lgkmcnt(0)" ::: "memory");
        __builtin_amdgcn_sched_barrier(0);
        __builtin_amdgcn_s_barrier();
        __builtin_amdgcn_sched_barrier(0);
        if (t + 2 < nt) STAGE(t & 1, (t + 2) * 32);
        __builtin_amdgcn_sched_barrier(0);
        __builtin_amdgcn_s_setprio(1);
#pragma unroll
        for (int kw = 0; kw < 2; kw++)
#pragma unroll
            for (int mi = 0; mi < 4; mi++)
#pragma unroll
                for (int nj = 0; nj < 2; nj++)
                    acc[mi][nj] = __builtin_amdgcn_mfma_f32_32x32x16_f16(af[mi][kw], bf[nj][kw], acc[mi][nj], 0, 0, 0);
        __builtin_amdgcn_s_setprio(0);
    }
#pragma unroll
    for (int mi = 0; mi < 4; mi++)
#pragma unroll
        for (int nj = 0; nj < 2; nj++)
#pragma unroll
            for (int r = 0; r < 16; r++) {
                int row = (r & 3) + 8 * (r >> 2) + 4 * lhi;
                out[((size_t)b * S_ + m0 + wrow * 128 + mi * 32 + row) * (size_t)D_
                    + n0 + wcol * 64 + nj * 32 + lrow] = acc[mi][nj][r];
            }
}

// ---------------- host ----------------
extern "C" void kernel_launch(void* const* d_in, const int* in_sizes, int n_in,
                              void* d_out, int out_size, void* d_ws, size_t ws_size,
                              hipStream_t stream) {
    const float* x    = (const float*)d_in[0];
    const float* W1   = (const float*)d_in[1];
    const float* b1   = (const float*)d_in[2];
    const float* lng  = (const float*)d_in[3];
    const float* lnb  = (const float*)d_in[4];
    const float* W2   = (const float*)d_in[5];
    const float* b2   = (const float*)d_in[6];
    const float* keys = (const float*)d_in[7];
    const float* patt = (const float*)d_in[8];
    const float* pw   = (const float*)d_in[9];
    const float* pout = (const float*)d_in[10];
    (void)in_sizes; (void)n_in; (void)out_size;

    char* w = (char*)d_ws;
    size_t off = 0;
    auto alloc = [&](size_t bytes) -> void* {
        void* p = w + off;
        off += (bytes + 255) & ~(size_t)255;
        return p;
    };
    double* gc64   = (double*)alloc((size_t)B_ * D_ * 8);
    float*  pmax   = (float*) alloc((size_t)B_ * 16 * D_ * 4);
    double* logits = (double*)alloc((size_t)B_ * NIN * 8);
    double* scores = (double*)alloc((size_t)B_ * NPROC * 8);
    double* hpre   = (double*)alloc((size_t)B_ * DR2 * 8);
    double* qs     = (double*)alloc((size_t)B_ * DR * 8);
    int*    iidx   = (int*)   alloc((size_t)B_ * KIN * 4);
    int*    pidx   = (int*)   alloc((size_t)B_ * KPROC * 4);
    _Float16* a16    = (_Float16*)alloc((size_t)B_ * S_ * KIN * 2);    // 67 MB
    _Float16* acts16 = (_Float16*)alloc((size_t)B_ * S_ * NPROC * 2);  // 67 MB
    _Float16* pout16 = (_Float16*)alloc((size_t)NPROC * D_ * 2);       // 8.4 MB
    char* u1 = (char*)alloc((size_t)67108864);
    _Float16* x16 = (_Float16*)u1;
    _Float16* ph  = (_Float16*)(u1 + 16777216);
    _Float16* pl  = (_Float16*)(u1 + 33554432);
    _Float16* WhT = (_Float16*)u1;               // thin path, one batch
    _Float16* WlT = (_Float16*)(u1 + 33554432);
    _Float16* sp  = (_Float16*)u1;
    _Float16* woT = (_Float16*)(u1 + 33554432);

    const size_t WSTRIDE = (size_t)NPROC * KIN;
    size_t off_before_fat = off;
    _Float16* WhA = (_Float16*)alloc((size_t)B_ * WSTRIDE * 2);
    _Float16* WlA = (_Float16*)alloc((size_t)B_ * WSTRIDE * 2);
    bool fat = (off <= ws_size);
    if (!fat) off = off_before_fat;

    hipMemsetAsync(scores, 0, (size_t)B_ * NPROC * 8, stream);

    k_conv_x16 <<<dim3((B_ * S_ * D_ / 4 + 255) / 256), 256, 0, stream>>>(x, x16, B_ * S_ * D_ / 4);
    k_conv_split<<<dim3((NIN * D_ + 255) / 256), 256, 0, stream>>>(patt, ph, pl, NIN * D_);
    k_conv_x16 <<<dim3((NPROC * D_ / 4 + 255) / 256), 256, 0, stream>>>(pout, pout16, NPROC * D_ / 4);

    k_max1<<<dim3(4, 16, 4), 256, 0, stream>>>(x, pmax);
    k_max2<<<dim3(4, 4), 256, 0, stream>>>(pmax, gc64);
    k_router1<<<dim3(128, 4), 256, 0, stream>>>(gc64, W1, b1, hpre);
    k_router2<<<dim3(4), 512, 0, stream>>>(hpre, lng, lnb, W2, b2, qs);
    k_router3<<<dim3(2048, 4), 256, 0, stream>>>(qs, keys, logits);
    k_topk<NIN, KIN><<<dim3(4), 1024, 0, stream>>>(logits, iidx);

    if (fat) {
        // one launch: D (z<4, MFMA-bound, dispatched first) + all-batch gatherW (z>=4, HBM-bound) overlap
        // gemmD grid is 8x32 per batch; gather units = 16384 = 64 z-slices of 256 blocks
        k_fusedDW<<<dim3(8, 32, 68), 256, 0, stream>>>(x16, ph, pl, iidx, a16, pw, WhA, WlA, WSTRIDE);
        k_gemmE<<<dim3(8, 32, 4), 256, 0, stream>>>(a16, WhA, WlA, acts16, scores, 0, WSTRIDE);
    } else {
        k_gemmD<<<dim3(8, 32, 4), 256, 0, stream>>>(x16, ph, pl, iidx, a16);
        for (int b = 0; b < 4; b++) {
            k_gatherW<<<dim3(NPROC, 1), 256, 0, stream>>>(pw, iidx, WhT, WlT, b, 0);
            k_gemmE<<<dim3(8, 32, 1), 256, 0, stream>>>(a16, WhT, WlT, acts16, scores, b, 0);
        }
    }

    k_topk<NPROC, KPROC><<<dim3(4), 1024, 0, stream>>>(scores, pidx);
    k_gatherSP<<<dim3(S_, 4), 256, 0, stream>>>(acts16, pidx, sp);
    k_gatherWoT<<<dim3(KPROC / 64, D_ / 64, 4), 256, 0, stream>>>(pout16, pidx, woT);
    k_gemmF<<<dim3(8, 8, 4), 256, 0, stream>>>(sp, woT, (float*)d_out);
}